// Round 1
// baseline (9916.381 us; speedup 1.0000x reference)
//
#include <hip/hip_runtime.h>
#include <hip/hip_bf16.h>
#include <hip/hip_cooperative_groups.h>

namespace cg = cooperative_groups;

typedef __bf16 bf16x8 __attribute__((ext_vector_type(8)));
typedef float  f32x4  __attribute__((ext_vector_type(4)));

#define NB    32                  // batch
#define NT    256                 // timesteps
#define NF    512                 // input features
#define NH    1024                // hidden
#define RINGSZ (NB * NH)          // elems per ring slot (bf16)
#define H2SZ  (NB * NT * NH)      // 8388608: h2 output elems
#define HHOFF H2SZ                // hh base in d_out
#define CCOFF (H2SZ + 2 * NB * NH)// cc base in d_out
#define LSTR  (NB * NH)           // layer stride inside hh/cc

__device__ __forceinline__ unsigned short f2bf(float f) {
  __bf16 h = (__bf16)f;
  return __builtin_bit_cast(unsigned short, h);
}

// ---------------- fp32 -> bf16 convert for x ----------------
__global__ void cvt_x_kernel(const float* __restrict__ x, unsigned short* __restrict__ xb) {
  long i = (long)(blockIdx.x * blockDim.x + threadIdx.x) * 8;
  float4 a = *reinterpret_cast<const float4*>(x + i);
  float4 b = *reinterpret_cast<const float4*>(x + i + 4);
  uint4 o;
  o.x = (unsigned)f2bf(a.x) | ((unsigned)f2bf(a.y) << 16);
  o.y = (unsigned)f2bf(a.z) | ((unsigned)f2bf(a.w) << 16);
  o.z = (unsigned)f2bf(b.x) | ((unsigned)f2bf(b.y) << 16);
  o.w = (unsigned)f2bf(b.z) | ((unsigned)f2bf(b.w) << 16);
  *reinterpret_cast<uint4*>(xb + i) = o;
}

// Preload this block's 16 gate rows of W [4H, K] into LDS as MFMA B-fragments.
// frag[ks*64 + lane] holds W[grow(lane&15)][ks*32 + (lane>>4)*8 + e], e=0..7 (bf16x8, 16B).
__device__ __forceinline__ void preload_frags(const float* __restrict__ W, bf16x8* dst,
                                              int ksteps, int K, int blk, int tid) {
  for (int idx = tid; idx < ksteps * 64; idx += 256) {
    int ks = idx >> 6, l = idx & 63;
    int n = l & 15;
    int kb = ks * 32 + (l >> 4) * 8;
    int grow = (n >> 2) * NH + blk * 4 + (n & 3);   // gate q = n>>2, unit v = n&3
    const float* p = W + (long)grow * K + kb;
    float4 a = *reinterpret_cast<const float4*>(p);
    float4 b = *reinterpret_cast<const float4*>(p + 4);
    bf16x8 fr;
    fr[0]=(__bf16)a.x; fr[1]=(__bf16)a.y; fr[2]=(__bf16)a.z; fr[3]=(__bf16)a.w;
    fr[4]=(__bf16)b.x; fr[5]=(__bf16)b.y; fr[6]=(__bf16)b.z; fr[7]=(__bf16)b.w;
    dst[idx] = fr;
  }
}

// K-subloop: 4 independent accumulator chains to cover dependent-MFMA latency.
template<int KSTEPS>
__device__ __forceinline__ void mac_loop(const unsigned short* __restrict__ arow,
                                         const bf16x8* bfr, int lane,
                                         f32x4& a0, f32x4& a1, f32x4& a2, f32x4& a3) {
  #pragma unroll
  for (int ks = 0; ks < KSTEPS; ks += 4) {
    bf16x8 x0 = *reinterpret_cast<const bf16x8*>(arow + (ks + 0) * 32);
    bf16x8 x1 = *reinterpret_cast<const bf16x8*>(arow + (ks + 1) * 32);
    bf16x8 x2 = *reinterpret_cast<const bf16x8*>(arow + (ks + 2) * 32);
    bf16x8 x3 = *reinterpret_cast<const bf16x8*>(arow + (ks + 3) * 32);
    a0 = __builtin_amdgcn_mfma_f32_16x16x32_bf16(x0, bfr[(ks + 0) * 64 + lane], a0, 0, 0, 0);
    a1 = __builtin_amdgcn_mfma_f32_16x16x32_bf16(x1, bfr[(ks + 1) * 64 + lane], a1, 0, 0, 0);
    a2 = __builtin_amdgcn_mfma_f32_16x16x32_bf16(x2, bfr[(ks + 2) * 64 + lane], a2, 0, 0, 0);
    a3 = __builtin_amdgcn_mfma_f32_16x16x32_bf16(x3, bfr[(ks + 3) * 64 + lane], a3, 0, 0, 0);
  }
}

__device__ __forceinline__ float sigm(float x) { return 1.f / (1.f + __expf(-x)); }

// Persistent fused 2-layer LSTM. 256 blocks x 256 threads, 1 block/CU.
// Block j owns hidden units 4j..4j+3 of BOTH layers. Layer pipelining:
// iteration s: layer0 computes t=s (waves 0,1), layer1 computes t=s-1 (waves 2,3).
__global__ __launch_bounds__(256, 1)
void lstm_fused_kernel(const unsigned short* __restrict__ xb,
                       const float* __restrict__ w0w, const float* __restrict__ w0b,
                       const float* __restrict__ u0w, const float* __restrict__ u0b,
                       const float* __restrict__ w1w, const float* __restrict__ w1b,
                       const float* __restrict__ u1w, const float* __restrict__ u1b,
                       float* __restrict__ out,
                       unsigned short* __restrict__ ring0,
                       unsigned short* __restrict__ ring1) {
  extern __shared__ char smem[];
  bf16x8* w0f = reinterpret_cast<bf16x8*>(smem);  // 16 ksteps (K=512)  -> 16KB
  bf16x8* u0f = w0f + 16 * 64;                    // 32 ksteps (K=1024) -> 32KB
  bf16x8* w1f = u0f + 32 * 64;                    // 32KB
  bf16x8* u1f = w1f + 32 * 64;                    // 32KB
  float*  g0  = reinterpret_cast<float*>(u1f + 32 * 64); // [32][17] fp32 gates L0
  float*  g1  = g0 + 32 * 17;                             // [32][17] fp32 gates L1

  const int tid  = threadIdx.x;
  const int blk  = blockIdx.x;
  const int wave = tid >> 6;
  const int lane = tid & 63;
  const int n16  = lane & 15;   // D col / B row (gate-row within slice)
  const int ksub = lane >> 4;   // k-subgroup

  // one-time weight staging (each weight element read exactly once grid-wide)
  preload_frags(w0w, w0f, 16, NF, blk, tid);
  preload_frags(u0w, u0f, 32, NH, blk, tid);
  preload_frags(w1w, w1f, 32, NH, blk, tid);
  preload_frags(u1w, u1f, 32, NH, blk, tid);
  __syncthreads();

  // per-thread state for phase 2: tid<128 -> layer0 (b=tid>>2, v=tid&3); tid>=128 -> layer1
  float bias0 = 0.f, bias1 = 0.f, bias2 = 0.f, bias3 = 0.f;
  int p2_b = 0, p2_v = 0, p2_hu = 0;
  if (tid < 128) {
    p2_b = tid >> 2; p2_v = tid & 3; p2_hu = blk * 4 + p2_v;
    bias0 = w0b[0 * NH + p2_hu] + u0b[0 * NH + p2_hu];
    bias1 = w0b[1 * NH + p2_hu] + u0b[1 * NH + p2_hu];
    bias2 = w0b[2 * NH + p2_hu] + u0b[2 * NH + p2_hu];
    bias3 = w0b[3 * NH + p2_hu] + u0b[3 * NH + p2_hu];
  } else {
    p2_b = (tid - 128) >> 2; p2_v = (tid - 128) & 3; p2_hu = blk * 4 + p2_v;
    bias0 = w1b[0 * NH + p2_hu] + u1b[0 * NH + p2_hu];
    bias1 = w1b[1 * NH + p2_hu] + u1b[1 * NH + p2_hu];
    bias2 = w1b[2 * NH + p2_hu] + u1b[2 * NH + p2_hu];
    bias3 = w1b[3 * NH + p2_hu] + u1b[3 * NH + p2_hu];
  }
  float c_state = 0.f;

  cg::grid_group grid = cg::this_grid();

  for (int s = 0; s <= NT; ++s) {
    // ---------------- phase 1: gate GEMMs ----------------
    if (wave < 2) {
      if (s < NT) {  // layer0, t = s: gates = x_t @ w0^T + h0[s-1] @ u0^T
        f32x4 a0 = {0.f,0.f,0.f,0.f}, a1 = a0, a2 = a0, a3 = a0;
        const int m0 = wave * 16 + n16;  // batch row this lane loads
        const unsigned short* xrow = xb + ((long)m0 * NT + s) * NF + ksub * 8;
        mac_loop<16>(xrow, w0f, lane, a0, a1, a2, a3);
        if (s > 0) {
          const unsigned short* hrow = ring0 + ((s - 1) & 1) * RINGSZ + m0 * NH + ksub * 8;
          mac_loop<32>(hrow, u0f, lane, a0, a1, a2, a3);
        }
        f32x4 acc = (a0 + a1) + (a2 + a3);
        #pragma unroll
        for (int r = 0; r < 4; ++r)
          g0[(wave * 16 + ksub * 4 + r) * 17 + n16] = acc[r];
      }
    } else {
      if (s >= 1) {  // layer1, t = s-1: gates = h0[s-1] @ w1^T + h1[s-2] @ u1^T
        f32x4 a0 = {0.f,0.f,0.f,0.f}, a1 = a0, a2 = a0, a3 = a0;
        const int m0 = (wave - 2) * 16 + n16;
        const unsigned short* arow = ring0 + ((s - 1) & 1) * RINGSZ + m0 * NH + ksub * 8;
        mac_loop<32>(arow, w1f, lane, a0, a1, a2, a3);
        if (s >= 2) {
          const unsigned short* brow = ring1 + (s & 1) * RINGSZ + m0 * NH + ksub * 8;
          mac_loop<32>(brow, u1f, lane, a0, a1, a2, a3);
        }
        f32x4 acc = (a0 + a1) + (a2 + a3);
        #pragma unroll
        for (int r = 0; r < 4; ++r)
          g1[((wave - 2) * 16 + ksub * 4 + r) * 17 + n16] = acc[r];
      }
    }
    __syncthreads();

    // ---------------- phase 2: activations + state update ----------------
    if (tid < 128) {
      if (s < NT) {
        float gi = sigm(g0[p2_b * 17 +  0 + p2_v] + bias0);
        float gf = sigm(g0[p2_b * 17 +  4 + p2_v] + bias1);
        float gg = tanhf(g0[p2_b * 17 +  8 + p2_v] + bias2);
        float go = sigm(g0[p2_b * 17 + 12 + p2_v] + bias3);
        c_state = gf * c_state + gi * gg;
        float h = go * tanhf(c_state);
        ring0[(s & 1) * RINGSZ + p2_b * NH + p2_hu] = f2bf(h);
        if (s == NT - 1) {
          out[HHOFF + 0 * LSTR + p2_b * NH + p2_hu] = h;
          out[CCOFF + 0 * LSTR + p2_b * NH + p2_hu] = c_state;
        }
      }
    } else {
      if (s >= 1) {
        int t = s - 1;
        float gi = sigm(g1[p2_b * 17 +  0 + p2_v] + bias0);
        float gf = sigm(g1[p2_b * 17 +  4 + p2_v] + bias1);
        float gg = tanhf(g1[p2_b * 17 +  8 + p2_v] + bias2);
        float go = sigm(g1[p2_b * 17 + 12 + p2_v] + bias3);
        c_state = gf * c_state + gi * gg;
        float h = go * tanhf(c_state);
        ring1[(t & 1) * RINGSZ + p2_b * NH + p2_hu] = f2bf(h);
        out[((long)p2_b * NT + t) * NH + p2_hu] = h;   // h2 output, fp32
        if (t == NT - 1) {
          out[HHOFF + 1 * LSTR + p2_b * NH + p2_hu] = h;
          out[CCOFF + 1 * LSTR + p2_b * NH + p2_hu] = c_state;
        }
      }
    }
    grid.sync();  // publishes ring writes for next iteration's phase 1
  }
}

extern "C" void kernel_launch(void* const* d_in, const int* in_sizes, int n_in,
                              void* d_out, int out_size, void* d_ws, size_t ws_size,
                              hipStream_t stream) {
  const float* x   = (const float*)d_in[0];
  const float* w0w = (const float*)d_in[1];
  const float* w0b = (const float*)d_in[2];
  const float* u0w = (const float*)d_in[3];
  const float* u0b = (const float*)d_in[4];
  const float* w1w = (const float*)d_in[5];
  const float* w1b = (const float*)d_in[6];
  const float* u1w = (const float*)d_in[7];
  const float* u1b = (const float*)d_in[8];
  float* out = (float*)d_out;

  // workspace layout (needs 8.25 MB): xb bf16 [32][256][512]; two h rings bf16 [2][32][1024]
  unsigned short* xb    = (unsigned short*)d_ws;
  unsigned short* ring0 = xb + (long)NB * NT * NF;
  unsigned short* ring1 = ring0 + 2 * RINGSZ;

  cvt_x_kernel<<<dim3((NB * NT * NF) / (256 * 8)), dim3(256), 0, stream>>>(x, xb);

  size_t smem = (size_t)(16 * 64 + 3 * 32 * 64) * sizeof(bf16x8) + 2 * 32 * 17 * sizeof(float);
  (void)hipFuncSetAttribute((const void*)lstm_fused_kernel,
                            hipFuncAttributeMaxDynamicSharedMemorySize, (int)smem);

  void* args[] = {&xb, &w0w, &w0b, &u0w, &u0b, &w1w, &w1b, &u1w, &u1b, &out, &ring0, &ring1};
  (void)hipLaunchCooperativeKernel((const void*)lstm_fused_kernel,
                                   dim3(256), dim3(256), args, (unsigned int)smem, stream);
}

// Round 2
// 6551.740 us; speedup vs baseline: 1.5135x; 1.5135x over previous
//
#include <hip/hip_runtime.h>
#include <hip/hip_bf16.h>

typedef __bf16 bf16x8 __attribute__((ext_vector_type(8)));
typedef float  f32x4  __attribute__((ext_vector_type(4)));

#define NB    32                  // batch
#define NT    256                 // timesteps
#define NF    512                 // input features
#define NH    1024                // hidden
#define NBLK  256                 // grid blocks (1 per CU)
#define RINGSZ (NB * NH)          // elems per ring slot (bf16)
#define H2SZ  (NB * NT * NH)      // 8388608: h2 output elems
#define HHOFF H2SZ                // hh base in d_out
#define CCOFF (H2SZ + 2 * NB * NH)// cc base in d_out
#define LSTR  (NB * NH)           // layer stride inside hh/cc

__device__ __forceinline__ unsigned short f2bf(float f) {
  __bf16 h = (__bf16)f;
  return __builtin_bit_cast(unsigned short, h);
}

// ---------------- fp32 -> bf16 convert for x; also zeroes the barrier counter ----------------
__global__ void cvt_x_kernel(const float* __restrict__ x, unsigned short* __restrict__ xb,
                             unsigned int* __restrict__ counter) {
  if (blockIdx.x == 0 && threadIdx.x == 0) *counter = 0;  // visible at kernel end (release)
  long i = (long)(blockIdx.x * blockDim.x + threadIdx.x) * 8;
  float4 a = *reinterpret_cast<const float4*>(x + i);
  float4 b = *reinterpret_cast<const float4*>(x + i + 4);
  uint4 o;
  o.x = (unsigned)f2bf(a.x) | ((unsigned)f2bf(a.y) << 16);
  o.y = (unsigned)f2bf(a.z) | ((unsigned)f2bf(a.w) << 16);
  o.z = (unsigned)f2bf(b.x) | ((unsigned)f2bf(b.y) << 16);
  o.w = (unsigned)f2bf(b.z) | ((unsigned)f2bf(b.w) << 16);
  *reinterpret_cast<uint4*>(xb + i) = o;
}

// Preload this block's 16 gate rows of W [4H, K] into LDS as MFMA B-fragments.
// frag[ks*64 + lane] holds W[grow(lane&15)][ks*32 + (lane>>4)*8 + e], e=0..7 (bf16x8, 16B).
__device__ __forceinline__ void preload_frags(const float* __restrict__ W, bf16x8* dst,
                                              int ksteps, int K, int blk, int tid) {
  for (int idx = tid; idx < ksteps * 64; idx += 256) {
    int ks = idx >> 6, l = idx & 63;
    int n = l & 15;
    int kb = ks * 32 + (l >> 4) * 8;
    int grow = (n >> 2) * NH + blk * 4 + (n & 3);   // gate q = n>>2, unit v = n&3
    const float* p = W + (long)grow * K + kb;
    float4 a = *reinterpret_cast<const float4*>(p);
    float4 b = *reinterpret_cast<const float4*>(p + 4);
    bf16x8 fr;
    fr[0]=(__bf16)a.x; fr[1]=(__bf16)a.y; fr[2]=(__bf16)a.z; fr[3]=(__bf16)a.w;
    fr[4]=(__bf16)b.x; fr[5]=(__bf16)b.y; fr[6]=(__bf16)b.z; fr[7]=(__bf16)b.w;
    dst[idx] = fr;
  }
}

// K-subloop: 4 independent accumulator chains to cover dependent-MFMA latency.
template<int KSTEPS>
__device__ __forceinline__ void mac_loop(const unsigned short* __restrict__ arow,
                                         const bf16x8* bfr, int lane,
                                         f32x4& a0, f32x4& a1, f32x4& a2, f32x4& a3) {
  #pragma unroll
  for (int ks = 0; ks < KSTEPS; ks += 4) {
    bf16x8 x0 = *reinterpret_cast<const bf16x8*>(arow + (ks + 0) * 32);
    bf16x8 x1 = *reinterpret_cast<const bf16x8*>(arow + (ks + 1) * 32);
    bf16x8 x2 = *reinterpret_cast<const bf16x8*>(arow + (ks + 2) * 32);
    bf16x8 x3 = *reinterpret_cast<const bf16x8*>(arow + (ks + 3) * 32);
    a0 = __builtin_amdgcn_mfma_f32_16x16x32_bf16(x0, bfr[(ks + 0) * 64 + lane], a0, 0, 0, 0);
    a1 = __builtin_amdgcn_mfma_f32_16x16x32_bf16(x1, bfr[(ks + 1) * 64 + lane], a1, 0, 0, 0);
    a2 = __builtin_amdgcn_mfma_f32_16x16x32_bf16(x2, bfr[(ks + 2) * 64 + lane], a2, 0, 0, 0);
    a3 = __builtin_amdgcn_mfma_f32_16x16x32_bf16(x3, bfr[(ks + 3) * 64 + lane], a3, 0, 0, 0);
  }
}

__device__ __forceinline__ float sigm(float x) { return 1.f / (1.f + __expf(-x)); }

// Persistent fused 2-layer LSTM. 256 blocks x 256 threads, 1 block/CU.
// Block j owns hidden units 4j..4j+3 of BOTH layers. Layer pipelining:
// iteration s: layer0 computes t=s (waves 0,1), layer1 computes t=s-1 (waves 2,3).
// Hand-rolled grid barrier: monotonic counter, release-add / relaxed-spin / acquire-fence.
__global__ __launch_bounds__(256, 1)
void lstm_fused_kernel(const unsigned short* __restrict__ xb,
                       const float* __restrict__ w0w, const float* __restrict__ w0b,
                       const float* __restrict__ u0w, const float* __restrict__ u0b,
                       const float* __restrict__ w1w, const float* __restrict__ w1b,
                       const float* __restrict__ u1w, const float* __restrict__ u1b,
                       float* __restrict__ out,
                       unsigned short* __restrict__ ring0,
                       unsigned short* __restrict__ ring1,
                       unsigned int* __restrict__ counter) {
  extern __shared__ char smem[];
  bf16x8* w0f = reinterpret_cast<bf16x8*>(smem);  // 16 ksteps (K=512)  -> 16KB
  bf16x8* u0f = w0f + 16 * 64;                    // 32 ksteps (K=1024) -> 32KB
  bf16x8* w1f = u0f + 32 * 64;                    // 32KB
  bf16x8* u1f = w1f + 32 * 64;                    // 32KB
  float*  g0  = reinterpret_cast<float*>(u1f + 32 * 64); // [32][17] fp32 gates L0
  float*  g1  = g0 + 32 * 17;                             // [32][17] fp32 gates L1

  const int tid  = threadIdx.x;
  const int blk  = blockIdx.x;
  const int wave = tid >> 6;
  const int lane = tid & 63;
  const int n16  = lane & 15;   // D col / B row (gate-row within slice)
  const int ksub = lane >> 4;   // k-subgroup

  // one-time weight staging (each weight element read exactly once grid-wide)
  preload_frags(w0w, w0f, 16, NF, blk, tid);
  preload_frags(u0w, u0f, 32, NH, blk, tid);
  preload_frags(w1w, w1f, 32, NH, blk, tid);
  preload_frags(u1w, u1f, 32, NH, blk, tid);
  __syncthreads();

  // per-thread state for phase 2: tid<128 -> layer0 (b=tid>>2, v=tid&3); tid>=128 -> layer1
  float bias0 = 0.f, bias1 = 0.f, bias2 = 0.f, bias3 = 0.f;
  int p2_b = 0, p2_v = 0, p2_hu = 0;
  if (tid < 128) {
    p2_b = tid >> 2; p2_v = tid & 3; p2_hu = blk * 4 + p2_v;
    bias0 = w0b[0 * NH + p2_hu] + u0b[0 * NH + p2_hu];
    bias1 = w0b[1 * NH + p2_hu] + u0b[1 * NH + p2_hu];
    bias2 = w0b[2 * NH + p2_hu] + u0b[2 * NH + p2_hu];
    bias3 = w0b[3 * NH + p2_hu] + u0b[3 * NH + p2_hu];
  } else {
    p2_b = (tid - 128) >> 2; p2_v = (tid - 128) & 3; p2_hu = blk * 4 + p2_v;
    bias0 = w1b[0 * NH + p2_hu] + u1b[0 * NH + p2_hu];
    bias1 = w1b[1 * NH + p2_hu] + u1b[1 * NH + p2_hu];
    bias2 = w1b[2 * NH + p2_hu] + u1b[2 * NH + p2_hu];
    bias3 = w1b[3 * NH + p2_hu] + u1b[3 * NH + p2_hu];
  }
  float c_state = 0.f;

  for (int s = 0; s <= NT; ++s) {
    // ---------------- phase 1: gate GEMMs ----------------
    if (wave < 2) {
      if (s < NT) {  // layer0, t = s: gates = x_t @ w0^T + h0[s-1] @ u0^T
        f32x4 a0 = {0.f,0.f,0.f,0.f}, a1 = a0, a2 = a0, a3 = a0;
        const int m0 = wave * 16 + n16;  // batch row this lane loads
        const unsigned short* xrow = xb + ((long)m0 * NT + s) * NF + ksub * 8;
        mac_loop<16>(xrow, w0f, lane, a0, a1, a2, a3);
        if (s > 0) {
          const unsigned short* hrow = ring0 + ((s - 1) & 1) * RINGSZ + m0 * NH + ksub * 8;
          mac_loop<32>(hrow, u0f, lane, a0, a1, a2, a3);
        }
        f32x4 acc = (a0 + a1) + (a2 + a3);
        #pragma unroll
        for (int r = 0; r < 4; ++r)
          g0[(wave * 16 + ksub * 4 + r) * 17 + n16] = acc[r];
      }
    } else {
      if (s >= 1) {  // layer1, t = s-1: gates = h0[s-1] @ w1^T + h1[s-2] @ u1^T
        f32x4 a0 = {0.f,0.f,0.f,0.f}, a1 = a0, a2 = a0, a3 = a0;
        const int m0 = (wave - 2) * 16 + n16;
        const unsigned short* arow = ring0 + ((s - 1) & 1) * RINGSZ + m0 * NH + ksub * 8;
        mac_loop<32>(arow, w1f, lane, a0, a1, a2, a3);
        if (s >= 2) {
          const unsigned short* brow = ring1 + (s & 1) * RINGSZ + m0 * NH + ksub * 8;
          mac_loop<32>(brow, u1f, lane, a0, a1, a2, a3);
        }
        f32x4 acc = (a0 + a1) + (a2 + a3);
        #pragma unroll
        for (int r = 0; r < 4; ++r)
          g1[((wave - 2) * 16 + ksub * 4 + r) * 17 + n16] = acc[r];
      }
    }
    __syncthreads();

    // ---------------- phase 2: activations + state update ----------------
    if (tid < 128) {
      if (s < NT) {
        float gi = sigm(g0[p2_b * 17 +  0 + p2_v] + bias0);
        float gf = sigm(g0[p2_b * 17 +  4 + p2_v] + bias1);
        float gg = tanhf(g0[p2_b * 17 +  8 + p2_v] + bias2);
        float go = sigm(g0[p2_b * 17 + 12 + p2_v] + bias3);
        c_state = gf * c_state + gi * gg;
        float h = go * tanhf(c_state);
        ring0[(s & 1) * RINGSZ + p2_b * NH + p2_hu] = f2bf(h);
        if (s == NT - 1) {
          out[HHOFF + 0 * LSTR + p2_b * NH + p2_hu] = h;
          out[CCOFF + 0 * LSTR + p2_b * NH + p2_hu] = c_state;
        }
      }
    } else {
      if (s >= 1) {
        int t = s - 1;
        float gi = sigm(g1[p2_b * 17 +  0 + p2_v] + bias0);
        float gf = sigm(g1[p2_b * 17 +  4 + p2_v] + bias1);
        float gg = tanhf(g1[p2_b * 17 +  8 + p2_v] + bias2);
        float go = sigm(g1[p2_b * 17 + 12 + p2_v] + bias3);
        c_state = gf * c_state + gi * gg;
        float h = go * tanhf(c_state);
        ring1[(t & 1) * RINGSZ + p2_b * NH + p2_hu] = f2bf(h);
        out[((long)p2_b * NT + t) * NH + p2_hu] = h;   // h2 output, fp32
        if (t == NT - 1) {
          out[HHOFF + 1 * LSTR + p2_b * NH + p2_hu] = h;
          out[CCOFF + 1 * LSTR + p2_b * NH + p2_hu] = c_state;
        }
      }
    }

    // ---------------- hand-rolled grid barrier ----------------
    if (s < NT) {
      __syncthreads();                       // all phase-2 stores issued + drained (vmcnt before s_barrier)
      if (tid == 0) {
        unsigned int target = (unsigned int)NBLK * (unsigned int)(s + 1);
        __hip_atomic_fetch_add(counter, 1u, __ATOMIC_RELEASE, __HIP_MEMORY_SCOPE_AGENT);
        while (__hip_atomic_load(counter, __ATOMIC_RELAXED, __HIP_MEMORY_SCOPE_AGENT) < target)
          __builtin_amdgcn_s_sleep(2);
      }
      __syncthreads();
      __builtin_amdgcn_fence(__ATOMIC_ACQUIRE, "agent");  // all threads: inv stale L1/L2 before ring reads
    }
  }
}

extern "C" void kernel_launch(void* const* d_in, const int* in_sizes, int n_in,
                              void* d_out, int out_size, void* d_ws, size_t ws_size,
                              hipStream_t stream) {
  const float* x   = (const float*)d_in[0];
  const float* w0w = (const float*)d_in[1];
  const float* w0b = (const float*)d_in[2];
  const float* u0w = (const float*)d_in[3];
  const float* u0b = (const float*)d_in[4];
  const float* w1w = (const float*)d_in[5];
  const float* w1b = (const float*)d_in[6];
  const float* u1w = (const float*)d_in[7];
  const float* u1b = (const float*)d_in[8];
  float* out = (float*)d_out;

  // workspace layout: [counter pad 128B][xb bf16 32*256*512][ring0 bf16 2*32*1024][ring1 same]
  unsigned int*   counter = (unsigned int*)d_ws;
  unsigned short* xb      = (unsigned short*)d_ws + 64;
  unsigned short* ring0   = xb + (long)NB * NT * NF;
  unsigned short* ring1   = ring0 + 2 * RINGSZ;

  cvt_x_kernel<<<dim3((NB * NT * NF) / (256 * 8)), dim3(256), 0, stream>>>(x, xb, counter);

  size_t smem = (size_t)(16 * 64 + 3 * 32 * 64) * sizeof(bf16x8) + 2 * 32 * 17 * sizeof(float);
  (void)hipFuncSetAttribute((const void*)lstm_fused_kernel,
                            hipFuncAttributeMaxDynamicSharedMemorySize, (int)smem);

  void* args[] = {&xb, &w0w, &w0b, &u0w, &u0b, &w1w, &w1b, &u1w, &u1b, &out,
                  &ring0, &ring1, &counter};
  (void)hipLaunchCooperativeKernel((const void*)lstm_fused_kernel,
                                   dim3(NBLK), dim3(256), args, (unsigned int)smem, stream);
}

// Round 3
// 4691.385 us; speedup vs baseline: 2.1137x; 1.3965x over previous
//
#include <hip/hip_runtime.h>
#include <hip/hip_bf16.h>

typedef __bf16 bf16x8 __attribute__((ext_vector_type(8)));
typedef float  f32x4  __attribute__((ext_vector_type(4)));
typedef unsigned long long u64x2 __attribute__((ext_vector_type(2)));

#define NB    32                  // batch
#define NT    256                 // timesteps
#define NF    512                 // input features
#define NH    1024                // hidden
#define NBLK  256                 // grid blocks (1 per CU)
#define NCTR  16                  // barrier counters (padded, 16 blocks each)
#define RINGSZ (NB * NH)          // elems per ring slot (bf16)
#define H2SZ  (NB * NT * NH)      // 8388608: h2 output elems
#define HHOFF H2SZ                // hh base in d_out
#define CCOFF (H2SZ + 2 * NB * NH)// cc base in d_out
#define LSTR  (NB * NH)           // layer stride inside hh/cc

__device__ __forceinline__ unsigned short f2bf(float f) {
  __bf16 h = (__bf16)f;
  return __builtin_bit_cast(unsigned short, h);
}

// 16B coherent (L2-bypassing, sc1) load from the h ring: two relaxed agent-scope
// 8B atomic loads -> global_load_dwordx2 sc1; compiler tracks vmcnt and pipelines.
__device__ __forceinline__ bf16x8 ld_ring16(const unsigned short* p) {
  const unsigned long long* q = (const unsigned long long*)p;
  u64x2 t;
  t[0] = __hip_atomic_load(q,     __ATOMIC_RELAXED, __HIP_MEMORY_SCOPE_AGENT);
  t[1] = __hip_atomic_load(q + 1, __ATOMIC_RELAXED, __HIP_MEMORY_SCOPE_AGENT);
  return __builtin_bit_cast(bf16x8, t);
}

// ---------------- fp32 -> bf16 convert for x; also zeroes barrier counters ----------------
__global__ void cvt_x_kernel(const float* __restrict__ x, unsigned short* __restrict__ xb,
                             unsigned int* __restrict__ counters) {
  if (blockIdx.x == 0) {  // zero 512 uints (16 counters padded to 128B each)
    counters[threadIdx.x] = 0;
    counters[256 + threadIdx.x] = 0;
  }
  long i = (long)(blockIdx.x * blockDim.x + threadIdx.x) * 8;
  float4 a = *reinterpret_cast<const float4*>(x + i);
  float4 b = *reinterpret_cast<const float4*>(x + i + 4);
  uint4 o;
  o.x = (unsigned)f2bf(a.x) | ((unsigned)f2bf(a.y) << 16);
  o.y = (unsigned)f2bf(a.z) | ((unsigned)f2bf(a.w) << 16);
  o.z = (unsigned)f2bf(b.x) | ((unsigned)f2bf(b.y) << 16);
  o.w = (unsigned)f2bf(b.z) | ((unsigned)f2bf(b.w) << 16);
  *reinterpret_cast<uint4*>(xb + i) = o;
}

// Preload this block's 16 gate rows of W [4H, K] into LDS as MFMA B-fragments.
// frag[ks*64 + lane] holds W[grow(lane&15)][ks*32 + (lane>>4)*8 + e], e=0..7 (bf16x8, 16B).
__device__ __forceinline__ void preload_frags(const float* __restrict__ W, bf16x8* dst,
                                              int ksteps, int K, int blk, int tid) {
  for (int idx = tid; idx < ksteps * 64; idx += 256) {
    int ks = idx >> 6, l = idx & 63;
    int n = l & 15;
    int kb = ks * 32 + (l >> 4) * 8;
    int grow = (n >> 2) * NH + blk * 4 + (n & 3);   // gate q = n>>2, unit v = n&3
    const float* p = W + (long)grow * K + kb;
    float4 a = *reinterpret_cast<const float4*>(p);
    float4 b = *reinterpret_cast<const float4*>(p + 4);
    bf16x8 fr;
    fr[0]=(__bf16)a.x; fr[1]=(__bf16)a.y; fr[2]=(__bf16)a.z; fr[3]=(__bf16)a.w;
    fr[4]=(__bf16)b.x; fr[5]=(__bf16)b.y; fr[6]=(__bf16)b.z; fr[7]=(__bf16)b.w;
    dst[idx] = fr;
  }
}

// K-subloop over plain cached loads (xb): 4 independent accumulator chains.
template<int KSTEPS>
__device__ __forceinline__ void mac_loop(const unsigned short* __restrict__ arow,
                                         const bf16x8* bfr, int lane,
                                         f32x4& a0, f32x4& a1, f32x4& a2, f32x4& a3) {
  #pragma unroll
  for (int ks = 0; ks < KSTEPS; ks += 4) {
    bf16x8 x0 = *reinterpret_cast<const bf16x8*>(arow + (ks + 0) * 32);
    bf16x8 x1 = *reinterpret_cast<const bf16x8*>(arow + (ks + 1) * 32);
    bf16x8 x2 = *reinterpret_cast<const bf16x8*>(arow + (ks + 2) * 32);
    bf16x8 x3 = *reinterpret_cast<const bf16x8*>(arow + (ks + 3) * 32);
    a0 = __builtin_amdgcn_mfma_f32_16x16x32_bf16(x0, bfr[(ks + 0) * 64 + lane], a0, 0, 0, 0);
    a1 = __builtin_amdgcn_mfma_f32_16x16x32_bf16(x1, bfr[(ks + 1) * 64 + lane], a1, 0, 0, 0);
    a2 = __builtin_amdgcn_mfma_f32_16x16x32_bf16(x2, bfr[(ks + 2) * 64 + lane], a2, 0, 0, 0);
    a3 = __builtin_amdgcn_mfma_f32_16x16x32_bf16(x3, bfr[(ks + 3) * 64 + lane], a3, 0, 0, 0);
  }
}

// Same, but A-rows come from the cross-block h ring via sc1 (coherent) loads.
template<int KSTEPS>
__device__ __forceinline__ void mac_loop_coh(const unsigned short* __restrict__ arow,
                                             const bf16x8* bfr, int lane,
                                             f32x4& a0, f32x4& a1, f32x4& a2, f32x4& a3) {
  #pragma unroll
  for (int ks = 0; ks < KSTEPS; ks += 4) {
    bf16x8 x0 = ld_ring16(arow + (ks + 0) * 32);
    bf16x8 x1 = ld_ring16(arow + (ks + 1) * 32);
    bf16x8 x2 = ld_ring16(arow + (ks + 2) * 32);
    bf16x8 x3 = ld_ring16(arow + (ks + 3) * 32);
    a0 = __builtin_amdgcn_mfma_f32_16x16x32_bf16(x0, bfr[(ks + 0) * 64 + lane], a0, 0, 0, 0);
    a1 = __builtin_amdgcn_mfma_f32_16x16x32_bf16(x1, bfr[(ks + 1) * 64 + lane], a1, 0, 0, 0);
    a2 = __builtin_amdgcn_mfma_f32_16x16x32_bf16(x2, bfr[(ks + 2) * 64 + lane], a2, 0, 0, 0);
    a3 = __builtin_amdgcn_mfma_f32_16x16x32_bf16(x3, bfr[(ks + 3) * 64 + lane], a3, 0, 0, 0);
  }
}

__device__ __forceinline__ float sigm(float x) { return 1.f / (1.f + __expf(-x)); }

// Persistent fused 2-layer LSTM. 256 blocks x 256 threads, 1 block/CU.
// Block j owns hidden units 4j..4j+3 of BOTH layers. Layer pipelining:
// iteration s: layer0 computes t=s (waves 0,1), layer1 computes t=s-1 (waves 2,3).
// Cross-block payload (h rings) is sc1-coherent; barrier is relaxed 16-counter
// arrive + poll. NO buffer_wbl2 / buffer_inv anywhere in the loop.
__global__ __launch_bounds__(256, 1)
void lstm_fused_kernel(const unsigned short* __restrict__ xb,
                       const float* __restrict__ w0w, const float* __restrict__ w0b,
                       const float* __restrict__ u0w, const float* __restrict__ u0b,
                       const float* __restrict__ w1w, const float* __restrict__ w1b,
                       const float* __restrict__ u1w, const float* __restrict__ u1b,
                       float* __restrict__ out,
                       unsigned short* __restrict__ ring0,
                       unsigned short* __restrict__ ring1,
                       unsigned int* __restrict__ counters) {
  extern __shared__ char smem[];
  bf16x8* w0f = reinterpret_cast<bf16x8*>(smem);  // 16 ksteps (K=512)  -> 16KB
  bf16x8* u0f = w0f + 16 * 64;                    // 32 ksteps (K=1024) -> 32KB
  bf16x8* w1f = u0f + 32 * 64;                    // 32KB
  bf16x8* u1f = w1f + 32 * 64;                    // 32KB
  float*  g0  = reinterpret_cast<float*>(u1f + 32 * 64); // [32][17] fp32 gates L0
  float*  g1  = g0 + 32 * 17;                             // [32][17] fp32 gates L1

  const int tid  = threadIdx.x;
  const int blk  = blockIdx.x;
  const int wave = tid >> 6;
  const int lane = tid & 63;
  const int n16  = lane & 15;   // D col / B row (gate-row within slice)
  const int ksub = lane >> 4;   // k-subgroup

  // one-time weight staging (each weight element read exactly once grid-wide)
  preload_frags(w0w, w0f, 16, NF, blk, tid);
  preload_frags(u0w, u0f, 32, NH, blk, tid);
  preload_frags(w1w, w1f, 32, NH, blk, tid);
  preload_frags(u1w, u1f, 32, NH, blk, tid);
  __syncthreads();

  // per-thread state for phase 2: tid<128 -> layer0 (b=tid>>2, v=tid&3); tid>=128 -> layer1
  float bias0 = 0.f, bias1 = 0.f, bias2 = 0.f, bias3 = 0.f;
  int p2_b = 0, p2_v = 0, p2_hu = 0;
  if (tid < 128) {
    p2_b = tid >> 2; p2_v = tid & 3; p2_hu = blk * 4 + p2_v;
    bias0 = w0b[0 * NH + p2_hu] + u0b[0 * NH + p2_hu];
    bias1 = w0b[1 * NH + p2_hu] + u0b[1 * NH + p2_hu];
    bias2 = w0b[2 * NH + p2_hu] + u0b[2 * NH + p2_hu];
    bias3 = w0b[3 * NH + p2_hu] + u0b[3 * NH + p2_hu];
  } else {
    p2_b = (tid - 128) >> 2; p2_v = (tid - 128) & 3; p2_hu = blk * 4 + p2_v;
    bias0 = w1b[0 * NH + p2_hu] + u1b[0 * NH + p2_hu];
    bias1 = w1b[1 * NH + p2_hu] + u1b[1 * NH + p2_hu];
    bias2 = w1b[2 * NH + p2_hu] + u1b[2 * NH + p2_hu];
    bias3 = w1b[3 * NH + p2_hu] + u1b[3 * NH + p2_hu];
  }
  float c_state = 0.f;

  unsigned int* myctr  = counters + (blk & (NCTR - 1)) * 32;   // 128B-padded counters
  unsigned int* pollp  = counters + (lane & (NCTR - 1)) * 32;

  for (int s = 0; s <= NT; ++s) {
    // ---------------- phase 1: gate GEMMs ----------------
    if (wave < 2) {
      if (s < NT) {  // layer0, t = s: gates = x_t @ w0^T + h0[s-1] @ u0^T
        f32x4 a0 = {0.f,0.f,0.f,0.f}, a1 = a0, a2 = a0, a3 = a0;
        const int m0 = wave * 16 + n16;  // batch row this lane loads
        const unsigned short* xrow = xb + ((long)m0 * NT + s) * NF + ksub * 8;
        mac_loop<16>(xrow, w0f, lane, a0, a1, a2, a3);
        if (s > 0) {
          const unsigned short* hrow = ring0 + ((s - 1) & 1) * RINGSZ + m0 * NH + ksub * 8;
          mac_loop_coh<32>(hrow, u0f, lane, a0, a1, a2, a3);
        }
        f32x4 acc = (a0 + a1) + (a2 + a3);
        #pragma unroll
        for (int r = 0; r < 4; ++r)
          g0[(wave * 16 + ksub * 4 + r) * 17 + n16] = acc[r];
      }
    } else {
      if (s >= 1) {  // layer1, t = s-1: gates = h0[s-1] @ w1^T + h1[s-2] @ u1^T
        f32x4 a0 = {0.f,0.f,0.f,0.f}, a1 = a0, a2 = a0, a3 = a0;
        const int m0 = (wave - 2) * 16 + n16;
        const unsigned short* arow = ring0 + ((s - 1) & 1) * RINGSZ + m0 * NH + ksub * 8;
        mac_loop_coh<32>(arow, w1f, lane, a0, a1, a2, a3);
        if (s >= 2) {
          const unsigned short* brow = ring1 + (s & 1) * RINGSZ + m0 * NH + ksub * 8;
          mac_loop_coh<32>(brow, u1f, lane, a0, a1, a2, a3);
        }
        f32x4 acc = (a0 + a1) + (a2 + a3);
        #pragma unroll
        for (int r = 0; r < 4; ++r)
          g1[((wave - 2) * 16 + ksub * 4 + r) * 17 + n16] = acc[r];
      }
    }
    __syncthreads();

    // ---------------- phase 2: activations + state update ----------------
    if (tid < 128) {
      if (s < NT) {
        float gi = sigm(g0[p2_b * 17 +  0 + p2_v] + bias0);
        float gf = sigm(g0[p2_b * 17 +  4 + p2_v] + bias1);
        float gg = tanhf(g0[p2_b * 17 +  8 + p2_v] + bias2);
        float go = sigm(g0[p2_b * 17 + 12 + p2_v] + bias3);
        c_state = gf * c_state + gi * gg;
        float h = go * tanhf(c_state);
        // pack two bf16 h values (v even with v+1) and store sc1-coherent
        unsigned hu16 = (unsigned)f2bf(h);
        unsigned other = __shfl_down(hu16, 1);
        if ((tid & 1) == 0) {
          unsigned pk = hu16 | (other << 16);
          __hip_atomic_store((unsigned*)(ring0 + (s & 1) * RINGSZ + p2_b * NH + p2_hu),
                             pk, __ATOMIC_RELAXED, __HIP_MEMORY_SCOPE_AGENT);
        }
        if (s == NT - 1) {
          out[HHOFF + 0 * LSTR + p2_b * NH + p2_hu] = h;
          out[CCOFF + 0 * LSTR + p2_b * NH + p2_hu] = c_state;
        }
      }
    } else {
      if (s >= 1) {
        int t = s - 1;
        float gi = sigm(g1[p2_b * 17 +  0 + p2_v] + bias0);
        float gf = sigm(g1[p2_b * 17 +  4 + p2_v] + bias1);
        float gg = tanhf(g1[p2_b * 17 +  8 + p2_v] + bias2);
        float go = sigm(g1[p2_b * 17 + 12 + p2_v] + bias3);
        c_state = gf * c_state + gi * gg;
        float h = go * tanhf(c_state);
        unsigned hu16 = (unsigned)f2bf(h);
        unsigned other = __shfl_down(hu16, 1);
        if ((tid & 1) == 0) {
          unsigned pk = hu16 | (other << 16);
          __hip_atomic_store((unsigned*)(ring1 + (t & 1) * RINGSZ + p2_b * NH + p2_hu),
                             pk, __ATOMIC_RELAXED, __HIP_MEMORY_SCOPE_AGENT);
        }
        out[((long)p2_b * NT + t) * NH + p2_hu] = h;   // h2 output, fp32 (cached)
        if (t == NT - 1) {
          out[HHOFF + 1 * LSTR + p2_b * NH + p2_hu] = h;
          out[CCOFF + 1 * LSTR + p2_b * NH + p2_hu] = c_state;
        }
      }
    }

    // ---------------- relaxed grid barrier (no cache maintenance) ----------------
    if (s < NT) {
      // sc1 store ack at vmcnt(0) == globally visible at the coherent point
      asm volatile("s_waitcnt vmcnt(0)" ::: "memory");
      __syncthreads();
      if (tid == 0)
        __hip_atomic_fetch_add(myctr, 1u, __ATOMIC_RELAXED, __HIP_MEMORY_SCOPE_AGENT);
      const unsigned target = (unsigned)(NBLK / NCTR) * (unsigned)(s + 1);
      for (;;) {
        unsigned v = __hip_atomic_load(pollp, __ATOMIC_RELAXED, __HIP_MEMORY_SCOPE_AGENT);
        if (__all(v >= target)) break;
        __builtin_amdgcn_s_sleep(2);
      }
      __syncthreads();  // compiler/memory ordering: no phase-1 reads hoisted above poll
    }
  }
}

extern "C" void kernel_launch(void* const* d_in, const int* in_sizes, int n_in,
                              void* d_out, int out_size, void* d_ws, size_t ws_size,
                              hipStream_t stream) {
  const float* x   = (const float*)d_in[0];
  const float* w0w = (const float*)d_in[1];
  const float* w0b = (const float*)d_in[2];
  const float* u0w = (const float*)d_in[3];
  const float* u0b = (const float*)d_in[4];
  const float* w1w = (const float*)d_in[5];
  const float* w1b = (const float*)d_in[6];
  const float* u1w = (const float*)d_in[7];
  const float* u1b = (const float*)d_in[8];
  float* out = (float*)d_out;

  // ws layout: [counters 512 uints (2KB)][xb bf16 32*256*512][ring0 bf16 2*32*1024][ring1 same]
  unsigned int*   counters = (unsigned int*)d_ws;
  unsigned short* xb       = (unsigned short*)d_ws + 1024;
  unsigned short* ring0    = xb + (long)NB * NT * NF;
  unsigned short* ring1    = ring0 + 2 * RINGSZ;

  cvt_x_kernel<<<dim3((NB * NT * NF) / (256 * 8)), dim3(256), 0, stream>>>(x, xb, counters);

  size_t smem = (size_t)(16 * 64 + 3 * 32 * 64) * sizeof(bf16x8) + 2 * 32 * 17 * sizeof(float);
  (void)hipFuncSetAttribute((const void*)lstm_fused_kernel,
                            hipFuncAttributeMaxDynamicSharedMemorySize, (int)smem);

  void* args[] = {&xb, &w0w, &w0b, &u0w, &u0b, &w1w, &w1b, &u1w, &u1b, &out,
                  &ring0, &ring1, &counters};
  (void)hipLaunchCooperativeKernel((const void*)lstm_fused_kernel,
                                   dim3(NBLK), dim3(256), args, (unsigned int)smem, stream);
}

// Round 4
// 3008.842 us; speedup vs baseline: 3.2957x; 1.5592x over previous
//
#include <hip/hip_runtime.h>
#include <hip/hip_bf16.h>

typedef __bf16 bf16x8 __attribute__((ext_vector_type(8)));
typedef float  f32x4  __attribute__((ext_vector_type(4)));

#define NB    32                  // batch
#define NT    256                 // timesteps
#define NF    512                 // input features
#define NH    1024                // hidden
#define NBLK  256                 // grid blocks (1 per CU)
#define NCTR  64                  // barrier counters (4 blocks each)
#define CTRPAD 32                 // uints per counter (128B padding)
#define HSEQSZ ((long)NB * NH)    // elems per timestep slab (bf16)
#define H2SZ  (NB * NT * NH)      // 8388608: h2 output elems
#define HHOFF H2SZ                // hh base in d_out
#define CCOFF (H2SZ + 2 * NB * NH)// cc base in d_out
#define LSTR  (NB * NH)           // layer stride inside hh/cc

__device__ __forceinline__ unsigned short f2bf(float f) {
  __bf16 h = (__bf16)f;
  return __builtin_bit_cast(unsigned short, h);
}

// ---------------- fp32 -> bf16 convert for x; also zeroes barrier counters ----------------
__global__ void cvt_x_kernel(const float* __restrict__ x, unsigned short* __restrict__ xb,
                             unsigned int* __restrict__ counters) {
  if (blockIdx.x == 0) {
    for (int i = threadIdx.x; i < NCTR * CTRPAD; i += 256) counters[i] = 0;
  }
  long i = (long)(blockIdx.x * blockDim.x + threadIdx.x) * 8;
  float4 a = *reinterpret_cast<const float4*>(x + i);
  float4 b = *reinterpret_cast<const float4*>(x + i + 4);
  uint4 o;
  o.x = (unsigned)f2bf(a.x) | ((unsigned)f2bf(a.y) << 16);
  o.y = (unsigned)f2bf(a.z) | ((unsigned)f2bf(a.w) << 16);
  o.z = (unsigned)f2bf(b.x) | ((unsigned)f2bf(b.y) << 16);
  o.w = (unsigned)f2bf(b.z) | ((unsigned)f2bf(b.w) << 16);
  *reinterpret_cast<uint4*>(xb + i) = o;
}

// Preload this block's 16 gate rows of W [4H, K] into LDS as MFMA B-fragments.
// frag[ks*64 + lane] holds W[grow(lane&15)][ks*32 + (lane>>4)*8 + e], e=0..7 (bf16x8, 16B).
__device__ __forceinline__ void preload_frags(const float* __restrict__ W, bf16x8* dst,
                                              int ksteps, int K, int blk, int tid) {
  for (int idx = tid; idx < ksteps * 64; idx += 256) {
    int ks = idx >> 6, l = idx & 63;
    int n = l & 15;
    int kb = ks * 32 + (l >> 4) * 8;
    int grow = (n >> 2) * NH + blk * 4 + (n & 3);   // gate q = n>>2, unit v = n&3
    const float* p = W + (long)grow * K + kb;
    float4 a = *reinterpret_cast<const float4*>(p);
    float4 b = *reinterpret_cast<const float4*>(p + 4);
    bf16x8 fr;
    fr[0]=(__bf16)a.x; fr[1]=(__bf16)a.y; fr[2]=(__bf16)a.z; fr[3]=(__bf16)a.w;
    fr[4]=(__bf16)b.x; fr[5]=(__bf16)b.y; fr[6]=(__bf16)b.z; fr[7]=(__bf16)b.w;
    dst[idx] = fr;
  }
}

// K-subloop, plain cached vector loads: 4 independent accumulator chains.
template<int KSTEPS>
__device__ __forceinline__ void mac_loop(const unsigned short* __restrict__ arow,
                                         const bf16x8* bfr, int lane,
                                         f32x4& a0, f32x4& a1, f32x4& a2, f32x4& a3) {
  #pragma unroll
  for (int ks = 0; ks < KSTEPS; ks += 4) {
    bf16x8 x0 = *reinterpret_cast<const bf16x8*>(arow + (ks + 0) * 32);
    bf16x8 x1 = *reinterpret_cast<const bf16x8*>(arow + (ks + 1) * 32);
    bf16x8 x2 = *reinterpret_cast<const bf16x8*>(arow + (ks + 2) * 32);
    bf16x8 x3 = *reinterpret_cast<const bf16x8*>(arow + (ks + 3) * 32);
    a0 = __builtin_amdgcn_mfma_f32_16x16x32_bf16(x0, bfr[(ks + 0) * 64 + lane], a0, 0, 0, 0);
    a1 = __builtin_amdgcn_mfma_f32_16x16x32_bf16(x1, bfr[(ks + 1) * 64 + lane], a1, 0, 0, 0);
    a2 = __builtin_amdgcn_mfma_f32_16x16x32_bf16(x2, bfr[(ks + 2) * 64 + lane], a2, 0, 0, 0);
    a3 = __builtin_amdgcn_mfma_f32_16x16x32_bf16(x3, bfr[(ks + 3) * 64 + lane], a3, 0, 0, 0);
  }
}

__device__ __forceinline__ float sigm(float x) { return 1.f / (1.f + __expf(-x)); }

// Persistent fused 2-layer LSTM. 256 blocks x 256 threads, 1 block/CU.
// Block j owns hidden units 4j..4j+3 of BOTH layers. Layer pipelining:
// iteration s: layer0 computes t=s (waves 0,1), layer1 computes t=s-1 (waves 2,3).
// h sequences live in DEEP write-once buffers: writes are sc1 (agent-scope
// relaxed atomic) straight to L3; reads are ordinary cached loads (safe: every
// address is read only after the barrier that follows its unique write, so no
// L2 can hold a stale copy). No cache-maintenance ops anywhere.
__global__ __launch_bounds__(256, 1)
void lstm_fused_kernel(const unsigned short* __restrict__ xb,
                       const float* __restrict__ w0w, const float* __restrict__ w0b,
                       const float* __restrict__ u0w, const float* __restrict__ u0b,
                       const float* __restrict__ w1w, const float* __restrict__ w1b,
                       const float* __restrict__ u1w, const float* __restrict__ u1b,
                       float* __restrict__ out,
                       unsigned short* __restrict__ h0seq,
                       unsigned short* __restrict__ h1seq,
                       unsigned int* __restrict__ counters) {
  extern __shared__ char smem[];
  bf16x8* w0f = reinterpret_cast<bf16x8*>(smem);  // 16 ksteps (K=512)  -> 16KB
  bf16x8* u0f = w0f + 16 * 64;                    // 32 ksteps (K=1024) -> 32KB
  bf16x8* w1f = u0f + 32 * 64;                    // 32KB
  bf16x8* u1f = w1f + 32 * 64;                    // 32KB
  float*  g0  = reinterpret_cast<float*>(u1f + 32 * 64); // [32][17] fp32 gates L0
  float*  g1  = g0 + 32 * 17;                             // [32][17] fp32 gates L1

  const int tid  = threadIdx.x;
  const int blk  = blockIdx.x;
  const int wave = tid >> 6;
  const int lane = tid & 63;
  const int n16  = lane & 15;   // D col / B row (gate-row within slice)
  const int ksub = lane >> 4;   // k-subgroup

  // one-time weight staging (each weight element read exactly once grid-wide)
  preload_frags(w0w, w0f, 16, NF, blk, tid);
  preload_frags(u0w, u0f, 32, NH, blk, tid);
  preload_frags(w1w, w1f, 32, NH, blk, tid);
  preload_frags(u1w, u1f, 32, NH, blk, tid);
  __syncthreads();

  // per-thread state for phase 2: tid<128 -> layer0 (b=tid>>2, v=tid&3); tid>=128 -> layer1
  float bias0 = 0.f, bias1 = 0.f, bias2 = 0.f, bias3 = 0.f;
  int p2_b = 0, p2_v = 0, p2_hu = 0;
  if (tid < 128) {
    p2_b = tid >> 2; p2_v = tid & 3; p2_hu = blk * 4 + p2_v;
    bias0 = w0b[0 * NH + p2_hu] + u0b[0 * NH + p2_hu];
    bias1 = w0b[1 * NH + p2_hu] + u0b[1 * NH + p2_hu];
    bias2 = w0b[2 * NH + p2_hu] + u0b[2 * NH + p2_hu];
    bias3 = w0b[3 * NH + p2_hu] + u0b[3 * NH + p2_hu];
  } else {
    p2_b = (tid - 128) >> 2; p2_v = (tid - 128) & 3; p2_hu = blk * 4 + p2_v;
    bias0 = w1b[0 * NH + p2_hu] + u1b[0 * NH + p2_hu];
    bias1 = w1b[1 * NH + p2_hu] + u1b[1 * NH + p2_hu];
    bias2 = w1b[2 * NH + p2_hu] + u1b[2 * NH + p2_hu];
    bias3 = w1b[3 * NH + p2_hu] + u1b[3 * NH + p2_hu];
  }
  float c_state = 0.f;

  unsigned int* myctr = counters + (blk  & (NCTR - 1)) * CTRPAD;
  unsigned int* pollp = counters + (lane & (NCTR - 1)) * CTRPAD;

  for (int s = 0; s <= NT; ++s) {
    // ---------------- phase 1: gate GEMMs ----------------
    if (wave < 2) {
      if (s < NT) {  // layer0, t = s: gates = x_t @ w0^T + h0[s-1] @ u0^T
        f32x4 a0 = {0.f,0.f,0.f,0.f}, a1 = a0, a2 = a0, a3 = a0;
        const int m0 = wave * 16 + n16;  // batch row this lane loads
        const unsigned short* xrow = xb + ((long)m0 * NT + s) * NF + ksub * 8;
        mac_loop<16>(xrow, w0f, lane, a0, a1, a2, a3);
        if (s > 0) {
          const unsigned short* hrow = h0seq + ((long)(s - 1) * NB + m0) * NH + ksub * 8;
          mac_loop<32>(hrow, u0f, lane, a0, a1, a2, a3);
        }
        f32x4 acc = (a0 + a1) + (a2 + a3);
        #pragma unroll
        for (int r = 0; r < 4; ++r)
          g0[(wave * 16 + ksub * 4 + r) * 17 + n16] = acc[r];
      }
    } else {
      if (s >= 1) {  // layer1, t = s-1: gates = h0[s-1] @ w1^T + h1[s-2] @ u1^T
        f32x4 a0 = {0.f,0.f,0.f,0.f}, a1 = a0, a2 = a0, a3 = a0;
        const int m0 = (wave - 2) * 16 + n16;
        const unsigned short* arow = h0seq + ((long)(s - 1) * NB + m0) * NH + ksub * 8;
        mac_loop<32>(arow, w1f, lane, a0, a1, a2, a3);
        if (s >= 2) {
          const unsigned short* brow = h1seq + ((long)(s - 2) * NB + m0) * NH + ksub * 8;
          mac_loop<32>(brow, u1f, lane, a0, a1, a2, a3);
        }
        f32x4 acc = (a0 + a1) + (a2 + a3);
        #pragma unroll
        for (int r = 0; r < 4; ++r)
          g1[((wave - 2) * 16 + ksub * 4 + r) * 17 + n16] = acc[r];
      }
    }
    __syncthreads();

    // ---------------- phase 2: activations + state update ----------------
    if (tid < 128) {
      if (s < NT) {
        float gi = sigm(g0[p2_b * 17 +  0 + p2_v] + bias0);
        float gf = sigm(g0[p2_b * 17 +  4 + p2_v] + bias1);
        float gg = tanhf(g0[p2_b * 17 +  8 + p2_v] + bias2);
        float go = sigm(g0[p2_b * 17 + 12 + p2_v] + bias3);
        c_state = gf * c_state + gi * gg;
        float h = go * tanhf(c_state);
        // pack two bf16 h (units v, v+1) -> one 4B sc1 store to the deep buffer
        unsigned hu16 = (unsigned)f2bf(h);
        unsigned other = __shfl_down(hu16, 1);
        if ((tid & 1) == 0) {
          unsigned pk = hu16 | (other << 16);
          __hip_atomic_store((unsigned*)(h0seq + (long)s * HSEQSZ + p2_b * NH + p2_hu),
                             pk, __ATOMIC_RELAXED, __HIP_MEMORY_SCOPE_AGENT);
        }
        if (s == NT - 1) {
          out[HHOFF + 0 * LSTR + p2_b * NH + p2_hu] = h;
          out[CCOFF + 0 * LSTR + p2_b * NH + p2_hu] = c_state;
        }
      }
    } else {
      if (s >= 1) {
        int t = s - 1;
        float gi = sigm(g1[p2_b * 17 +  0 + p2_v] + bias0);
        float gf = sigm(g1[p2_b * 17 +  4 + p2_v] + bias1);
        float gg = tanhf(g1[p2_b * 17 +  8 + p2_v] + bias2);
        float go = sigm(g1[p2_b * 17 + 12 + p2_v] + bias3);
        c_state = gf * c_state + gi * gg;
        float h = go * tanhf(c_state);
        unsigned hu16 = (unsigned)f2bf(h);
        unsigned other = __shfl_down(hu16, 1);
        if ((tid & 1) == 0) {
          unsigned pk = hu16 | (other << 16);
          __hip_atomic_store((unsigned*)(h1seq + (long)t * HSEQSZ + p2_b * NH + p2_hu),
                             pk, __ATOMIC_RELAXED, __HIP_MEMORY_SCOPE_AGENT);
        }
        // NOTE: no h2 store here — done as a coalesced sweep after the loop.
        if (t == NT - 1) {
          out[HHOFF + 1 * LSTR + p2_b * NH + p2_hu] = h;
          out[CCOFF + 1 * LSTR + p2_b * NH + p2_hu] = c_state;
        }
      }
    }

    // ---------------- relaxed grid barrier (no cache maintenance) ----------------
    {
      // sc1 store ack at vmcnt(0) == globally visible at the coherent point
      asm volatile("s_waitcnt vmcnt(0)" ::: "memory");
      __syncthreads();
      if (tid == 0)
        __hip_atomic_fetch_add(myctr, 1u, __ATOMIC_RELAXED, __HIP_MEMORY_SCOPE_AGENT);
      const unsigned target = (unsigned)(NBLK / NCTR) * (unsigned)(s + 1);
      for (;;) {
        unsigned v = __hip_atomic_load(pollp, __ATOMIC_RELAXED, __HIP_MEMORY_SCOPE_AGENT);
        if (__all(v >= target)) break;
        __builtin_amdgcn_s_sleep(1);
      }
      __syncthreads();  // compiler fence: no post-barrier reads hoisted above poll
    }
  }

  // ---------------- epilogue: coalesced h2 write (bf16 h1seq -> fp32 out) ----------------
  // Block j owns timestep t=j: out[b][j][:] = fp32(h1seq[j][b][:]). Fully
  // coalesced 16B reads / 32B writes; no partial cache lines.
  {
    const long src_base = (long)blk * HSEQSZ;
    for (int i = tid; i < (NB * NH) / 8; i += 256) {
      int e = i * 8;
      int b = e >> 10;          // e / NH
      int h = e & (NH - 1);
      bf16x8 v = *reinterpret_cast<const bf16x8*>(h0seq + 0 * 0 + src_base + e) ; // placeholder avoided below
      // (read from h1seq — see next line; kept single-assignment for clarity)
      v = *reinterpret_cast<const bf16x8*>(h1seq + src_base + e);
      float4 lo, hi;
      lo.x = (float)v[0]; lo.y = (float)v[1]; lo.z = (float)v[2]; lo.w = (float)v[3];
      hi.x = (float)v[4]; hi.y = (float)v[5]; hi.z = (float)v[6]; hi.w = (float)v[7];
      float* dst = out + ((long)b * NT + blk) * NH + h;
      *reinterpret_cast<float4*>(dst)     = lo;
      *reinterpret_cast<float4*>(dst + 4) = hi;
    }
  }
}

extern "C" void kernel_launch(void* const* d_in, const int* in_sizes, int n_in,
                              void* d_out, int out_size, void* d_ws, size_t ws_size,
                              hipStream_t stream) {
  const float* x   = (const float*)d_in[0];
  const float* w0w = (const float*)d_in[1];
  const float* w0b = (const float*)d_in[2];
  const float* u0w = (const float*)d_in[3];
  const float* u0b = (const float*)d_in[4];
  const float* w1w = (const float*)d_in[5];
  const float* w1b = (const float*)d_in[6];
  const float* u1w = (const float*)d_in[7];
  const float* u1b = (const float*)d_in[8];
  float* out = (float*)d_out;

  // ws layout: [counters 8KB][xb bf16 32*256*512 = 8.4MB][h0seq bf16 256*32*1024 = 16.8MB][h1seq same]
  unsigned int*   counters = (unsigned int*)d_ws;
  unsigned short* xb       = (unsigned short*)d_ws + NCTR * CTRPAD * 2;
  unsigned short* h0seq    = xb + (long)NB * NT * NF;
  unsigned short* h1seq    = h0seq + (long)NT * HSEQSZ;

  cvt_x_kernel<<<dim3((NB * NT * NF) / (256 * 8)), dim3(256), 0, stream>>>(x, xb, counters);

  size_t smem = (size_t)(16 * 64 + 3 * 32 * 64) * sizeof(bf16x8) + 2 * 32 * 17 * sizeof(float);
  (void)hipFuncSetAttribute((const void*)lstm_fused_kernel,
                            hipFuncAttributeMaxDynamicSharedMemorySize, (int)smem);

  void* args[] = {&xb, &w0w, &w0b, &u0w, &u0b, &w1w, &w1b, &u1w, &u1b, &out,
                  &h0seq, &h1seq, &counters};
  (void)hipLaunchCooperativeKernel((const void*)lstm_fused_kernel,
                                   dim3(NBLK), dim3(256), args, (unsigned int)smem, stream);
}

// Round 6
// 2663.062 us; speedup vs baseline: 3.7237x; 1.1298x over previous
//
#include <hip/hip_runtime.h>
#include <hip/hip_bf16.h>

typedef __bf16 bf16x8 __attribute__((ext_vector_type(8)));
typedef float  f32x4  __attribute__((ext_vector_type(4)));

#define NB    32                  // batch
#define NT    256                 // timesteps
#define NF    512                 // input features
#define NH    1024                // hidden
#define NBLK  256                 // grid blocks (1 per CU)
#define NTHR  512                 // threads per block (8 waves)
#define NCTR  64                  // barrier counters (4 blocks each)
#define CTRPAD 32                 // uints per counter (128B padding)
#define HSEQSZ ((long)NB * NH)    // elems per timestep slab (bf16)
#define H2SZ  (NB * NT * NH)      // h2 output elems
#define HHOFF H2SZ                // hh base in d_out
#define CCOFF (H2SZ + 2 * NB * NH)// cc base in d_out
#define LSTR  (NB * NH)           // layer stride inside hh/cc

__device__ __forceinline__ unsigned short f2bf(float f) {
  __bf16 h = (__bf16)f;
  return __builtin_bit_cast(unsigned short, h);
}

// ---------------- fp32 -> bf16 convert for x; also zeroes barrier counters ----------------
__global__ void cvt_x_kernel(const float* __restrict__ x, unsigned short* __restrict__ xb,
                             unsigned int* __restrict__ counters) {
  if (blockIdx.x == 0) {
    for (int i = threadIdx.x; i < NCTR * CTRPAD; i += 256) counters[i] = 0;
  }
  long i = (long)(blockIdx.x * blockDim.x + threadIdx.x) * 8;
  float4 a = *reinterpret_cast<const float4*>(x + i);
  float4 b = *reinterpret_cast<const float4*>(x + i + 4);
  uint4 o;
  o.x = (unsigned)f2bf(a.x) | ((unsigned)f2bf(a.y) << 16);
  o.y = (unsigned)f2bf(a.z) | ((unsigned)f2bf(a.w) << 16);
  o.z = (unsigned)f2bf(b.x) | ((unsigned)f2bf(b.y) << 16);
  o.w = (unsigned)f2bf(b.z) | ((unsigned)f2bf(b.w) << 16);
  *reinterpret_cast<uint4*>(xb + i) = o;
}

// Load N MFMA B-fragments for this wave into REGISTERS (fp32 global -> bf16).
// dst[ks] holds W[grow][kofs + ks*32 + ksub*8 .. +8).
template<int N>
__device__ __forceinline__ void load_wfrags(const float* __restrict__ W, int K, int kofs,
                                            int grow, int ksub, bf16x8* dst) {
#pragma unroll
  for (int ks = 0; ks < N; ++ks) {
    const float* p = W + (long)grow * K + kofs + ks * 32 + ksub * 8;
    float4 a = *reinterpret_cast<const float4*>(p);
    float4 b = *reinterpret_cast<const float4*>(p + 4);
    bf16x8 fr;
    fr[0]=(__bf16)a.x; fr[1]=(__bf16)a.y; fr[2]=(__bf16)a.z; fr[3]=(__bf16)a.w;
    fr[4]=(__bf16)b.x; fr[5]=(__bf16)b.y; fr[6]=(__bf16)b.z; fr[7]=(__bf16)b.w;
    dst[ks] = fr;
  }
}

// 8 ksteps: stage 8 A-fragments (8 outstanding loads), then 8 MFMAs, 4 acc chains.
__device__ __forceinline__ void mac8(const unsigned short* __restrict__ ap,
                                     const bf16x8* wr, f32x4* ac) {
  bf16x8 st[8];
#pragma unroll
  for (int j = 0; j < 8; ++j) st[j] = *reinterpret_cast<const bf16x8*>(ap + j * 32);
#pragma unroll
  for (int j = 0; j < 8; ++j)
    ac[j & 3] = __builtin_amdgcn_mfma_f32_16x16x32_bf16(st[j], wr[j], ac[j & 3], 0, 0, 0);
}

__device__ __forceinline__ float sigm(float x) { return 1.f / (1.f + __expf(-x)); }

// Persistent fused 2-layer LSTM. 256 blocks x 512 threads (8 waves), 1 block/CU.
// Block j owns hidden units 4j..4j+3 of BOTH layers. Weights live in REGISTERS
// (per-wave B-fragments). Wave tasks (rt = wave&1 picks batch rows rt*16..+16):
//   w0/w1: L0  g0p0 = x_t@w0 (computed during previous barrier) + h0[s-1]@u0[k<512]
//   w2/w3: L0  g0p1 = h0[s-1]@u0[k>=512]
//   w4/w5: L1  g1p0 = h0[s-1]@w1      (t = s-1)
//   w6/w7: L1  g1p1 = h1[s-2]@u1
// Cross-block h: sc1 writes to deep write-once buffers, plain cached reads after
// the barrier. Barrier: relaxed 64-counter arrive, wave-7-only poll.
__global__ __launch_bounds__(NTHR, 2)
void lstm_fused_kernel(const unsigned short* __restrict__ xb,
                       const float* __restrict__ w0w, const float* __restrict__ w0b,
                       const float* __restrict__ u0w, const float* __restrict__ u0b,
                       const float* __restrict__ w1w, const float* __restrict__ w1b,
                       const float* __restrict__ u1w, const float* __restrict__ u1b,
                       float* __restrict__ out,
                       unsigned short* __restrict__ h0seq,
                       unsigned short* __restrict__ h1seq,
                       unsigned int* __restrict__ counters) {
  __shared__ float gbuf[4][32 * 17];   // g0p0, g0p1, g1p0, g1p1

  const int tid  = threadIdx.x;
  const int blk  = blockIdx.x;
  const int wave = tid >> 6;
  const int lane = tid & 63;
  const int n16  = lane & 15;   // gate-col within slice / A row
  const int ksub = lane >> 4;   // k-subgroup
  const int rt   = wave & 1;    // batch row-tile
  const int m0   = rt * 16 + n16;
  const int grow = (n16 >> 2) * NH + blk * 4 + (n16 & 3);

  // -------- one-time: weights into registers --------
  bf16x8 wreg[32];
  if (wave < 2) {
    load_wfrags<16>(w0w, NF, 0,   grow, ksub, wreg);       // x-proj (K=512)
    load_wfrags<16>(u0w, NH, 0,   grow, ksub, wreg + 16);  // h-part, k 0..511
  } else if (wave < 4) {
    load_wfrags<16>(u0w, NH, 512, grow, ksub, wreg);       // h-part, k 512..1023
  } else if (wave < 6) {
    load_wfrags<32>(w1w, NH, 0,   grow, ksub, wreg);       // L1 input-proj
  } else {
    load_wfrags<32>(u1w, NH, 0,   grow, ksub, wreg);       // L1 recurrence
  }

  // -------- per-thread phase-2 state --------
  float bias0 = 0.f, bias1 = 0.f, bias2 = 0.f, bias3 = 0.f;
  int p2_b = 0, p2_v = 0, p2_hu = 0;
  if (tid < 128) {
    p2_b = tid >> 2; p2_v = tid & 3; p2_hu = blk * 4 + p2_v;
    bias0 = w0b[0 * NH + p2_hu] + u0b[0 * NH + p2_hu];
    bias1 = w0b[1 * NH + p2_hu] + u0b[1 * NH + p2_hu];
    bias2 = w0b[2 * NH + p2_hu] + u0b[2 * NH + p2_hu];
    bias3 = w0b[3 * NH + p2_hu] + u0b[3 * NH + p2_hu];
  } else if (tid < 256) {
    p2_b = (tid - 128) >> 2; p2_v = (tid - 128) & 3; p2_hu = blk * 4 + p2_v;
    bias0 = w1b[0 * NH + p2_hu] + u1b[0 * NH + p2_hu];
    bias1 = w1b[1 * NH + p2_hu] + u1b[1 * NH + p2_hu];
    bias2 = w1b[2 * NH + p2_hu] + u1b[2 * NH + p2_hu];
    bias3 = w1b[3 * NH + p2_hu] + u1b[3 * NH + p2_hu];
  }
  float c_state = 0.f;

  // -------- prologue: x-projection for t=0 (w0/w1) --------
  f32x4 xa[4];
#pragma unroll
  for (int r = 0; r < 4; ++r) xa[r] = (f32x4){0.f, 0.f, 0.f, 0.f};
  if (wave < 2) {
    const unsigned short* xp = xb + ((long)m0 * NT + 0) * NF + ksub * 8;
    mac8(xp, wreg, xa); mac8(xp + 256, wreg + 8, xa);
  }

  for (int s = 0; s <= NT; ++s) {
    // ---------------- phase 1: gate GEMM partials ----------------
    if (wave < 2) {
      if (s < NT) {
        f32x4 ac[4] = {xa[0], xa[1], xa[2], xa[3]};
        if (s > 0) {
          const unsigned short* ap = h0seq + (long)(s - 1) * HSEQSZ + m0 * NH + ksub * 8;
          mac8(ap, wreg + 16, ac); mac8(ap + 256, wreg + 24, ac);
        }
        f32x4 acc = (ac[0] + ac[1]) + (ac[2] + ac[3]);
#pragma unroll
        for (int r = 0; r < 4; ++r) gbuf[0][(rt * 16 + ksub * 4 + r) * 17 + n16] = acc[r];
      }
    } else if (wave < 4) {
      if (s < NT) {
        f32x4 ac[4];
#pragma unroll
        for (int r = 0; r < 4; ++r) ac[r] = (f32x4){0.f, 0.f, 0.f, 0.f};
        if (s > 0) {
          const unsigned short* ap = h0seq + (long)(s - 1) * HSEQSZ + m0 * NH + 512 + ksub * 8;
          mac8(ap, wreg, ac); mac8(ap + 256, wreg + 8, ac);
        }
        f32x4 acc = (ac[0] + ac[1]) + (ac[2] + ac[3]);
#pragma unroll
        for (int r = 0; r < 4; ++r) gbuf[1][(rt * 16 + ksub * 4 + r) * 17 + n16] = acc[r];
      }
    } else if (wave < 6) {
      if (s >= 1) {
        f32x4 ac[4];
#pragma unroll
        for (int r = 0; r < 4; ++r) ac[r] = (f32x4){0.f, 0.f, 0.f, 0.f};
        const unsigned short* ap = h0seq + (long)(s - 1) * HSEQSZ + m0 * NH + ksub * 8;
        mac8(ap, wreg, ac);        mac8(ap + 256, wreg + 8,  ac);
        mac8(ap + 512, wreg + 16, ac); mac8(ap + 768, wreg + 24, ac);
        f32x4 acc = (ac[0] + ac[1]) + (ac[2] + ac[3]);
#pragma unroll
        for (int r = 0; r < 4; ++r) gbuf[2][(rt * 16 + ksub * 4 + r) * 17 + n16] = acc[r];
      }
    } else {
      if (s >= 1) {
        f32x4 ac[4];
#pragma unroll
        for (int r = 0; r < 4; ++r) ac[r] = (f32x4){0.f, 0.f, 0.f, 0.f};
        if (s >= 2) {
          const unsigned short* ap = h1seq + (long)(s - 2) * HSEQSZ + m0 * NH + ksub * 8;
          mac8(ap, wreg, ac);        mac8(ap + 256, wreg + 8,  ac);
          mac8(ap + 512, wreg + 16, ac); mac8(ap + 768, wreg + 24, ac);
        }
        f32x4 acc = (ac[0] + ac[1]) + (ac[2] + ac[3]);
#pragma unroll
        for (int r = 0; r < 4; ++r) gbuf[3][(rt * 16 + ksub * 4 + r) * 17 + n16] = acc[r];
      }
    }
    __syncthreads();

    // ---------------- phase 2: activations + state update ----------------
    if (tid < 128) {
      if (s < NT) {
        int base = p2_b * 17;
        float gi = sigm(gbuf[0][base +  0 + p2_v] + gbuf[1][base +  0 + p2_v] + bias0);
        float gf = sigm(gbuf[0][base +  4 + p2_v] + gbuf[1][base +  4 + p2_v] + bias1);
        float gg = tanhf(gbuf[0][base +  8 + p2_v] + gbuf[1][base +  8 + p2_v] + bias2);
        float go = sigm(gbuf[0][base + 12 + p2_v] + gbuf[1][base + 12 + p2_v] + bias3);
        c_state = gf * c_state + gi * gg;
        float h = go * tanhf(c_state);
        unsigned hu16 = (unsigned)f2bf(h);
        unsigned other = __shfl_down(hu16, 1);
        if ((tid & 1) == 0) {
          unsigned pk = hu16 | (other << 16);
          __hip_atomic_store((unsigned*)(h0seq + (long)s * HSEQSZ + p2_b * NH + p2_hu),
                             pk, __ATOMIC_RELAXED, __HIP_MEMORY_SCOPE_AGENT);
        }
        if (s == NT - 1) {
          out[HHOFF + 0 * LSTR + p2_b * NH + p2_hu] = h;
          out[CCOFF + 0 * LSTR + p2_b * NH + p2_hu] = c_state;
        }
      }
    } else if (tid < 256) {
      if (s >= 1) {
        int t = s - 1;
        int base = p2_b * 17;
        float gi = sigm(gbuf[2][base +  0 + p2_v] + gbuf[3][base +  0 + p2_v] + bias0);
        float gf = sigm(gbuf[2][base +  4 + p2_v] + gbuf[3][base +  4 + p2_v] + bias1);
        float gg = tanhf(gbuf[2][base +  8 + p2_v] + gbuf[3][base +  8 + p2_v] + bias2);
        float go = sigm(gbuf[2][base + 12 + p2_v] + gbuf[3][base + 12 + p2_v] + bias3);
        c_state = gf * c_state + gi * gg;
        float h = go * tanhf(c_state);
        unsigned hu16 = (unsigned)f2bf(h);
        unsigned other = __shfl_down(hu16, 1);
        if ((tid & 1) == 0) {
          unsigned pk = hu16 | (other << 16);
          __hip_atomic_store((unsigned*)(h1seq + (long)t * HSEQSZ + p2_b * NH + p2_hu),
                             pk, __ATOMIC_RELAXED, __HIP_MEMORY_SCOPE_AGENT);
        }
        if (t == NT - 1) {
          out[HHOFF + 1 * LSTR + p2_b * NH + p2_hu] = h;
          out[CCOFF + 1 * LSTR + p2_b * NH + p2_hu] = c_state;
        }
      }
    }

    // ---------------- grid barrier (relaxed; x-proj for s+1 hides under it) ----------------
    {
      if (wave < 4) asm volatile("s_waitcnt vmcnt(0)" ::: "memory");  // drain sc1 h stores
      __syncthreads();
      if (tid == 0)
        __hip_atomic_fetch_add(counters + (blk & (NCTR - 1)) * CTRPAD, 1u,
                               __ATOMIC_RELAXED, __HIP_MEMORY_SCOPE_AGENT);
      if (wave < 2) {   // compute next timestep's x-projection while waiting
#pragma unroll
        for (int r = 0; r < 4; ++r) xa[r] = (f32x4){0.f, 0.f, 0.f, 0.f};
        if (s + 1 < NT) {
          const unsigned short* xp = xb + ((long)m0 * NT + (s + 1)) * NF + ksub * 8;
          mac8(xp, wreg, xa); mac8(xp + 256, wreg + 8, xa);
        }
      }
      if (wave == 7) {  // single-wave poll: lane l watches counter l
        const unsigned target = (unsigned)(NBLK / NCTR) * (unsigned)(s + 1);
        unsigned int* pp = counters + (lane & (NCTR - 1)) * CTRPAD;
        for (;;) {
          unsigned v = __hip_atomic_load(pp, __ATOMIC_RELAXED, __HIP_MEMORY_SCOPE_AGENT);
          if (__all(v >= target)) break;
          __builtin_amdgcn_s_sleep(1);
        }
      }
      __syncthreads();
    }
  }

  // ---------------- epilogue: coalesced h2 write (bf16 h1seq -> fp32 out) ----------------
  // Block j owns timestep t=j: out[b][j][:] = fp32(h1seq[j][b][:]).
  {
    const long src_base = (long)blk * HSEQSZ;
    for (int i = tid; i < (NB * NH) / 8; i += NTHR) {
      int e = i * 8;
      int b = e >> 10;          // e / NH
      int h = e & (NH - 1);
      bf16x8 v = *reinterpret_cast<const bf16x8*>(h1seq + src_base + e);
      float4 lo, hi;
      lo.x = (float)v[0]; lo.y = (float)v[1]; lo.z = (float)v[2]; lo.w = (float)v[3];
      hi.x = (float)v[4]; hi.y = (float)v[5]; hi.z = (float)v[6]; hi.w = (float)v[7];
      float* dst = out + ((long)b * NT + blk) * NH + h;
      *reinterpret_cast<float4*>(dst)     = lo;
      *reinterpret_cast<float4*>(dst + 4) = hi;
    }
  }
}

extern "C" void kernel_launch(void* const* d_in, const int* in_sizes, int n_in,
                              void* d_out, int out_size, void* d_ws, size_t ws_size,
                              hipStream_t stream) {
  const float* x   = (const float*)d_in[0];
  const float* w0w = (const float*)d_in[1];
  const float* w0b = (const float*)d_in[2];
  const float* u0w = (const float*)d_in[3];
  const float* u0b = (const float*)d_in[4];
  const float* w1w = (const float*)d_in[5];
  const float* w1b = (const float*)d_in[6];
  const float* u1w = (const float*)d_in[7];
  const float* u1b = (const float*)d_in[8];
  float* out = (float*)d_out;

  // ws layout: [counters 8KB][xb bf16 8.4MB][h0seq bf16 16.8MB][h1seq bf16 16.8MB]
  unsigned int*   counters = (unsigned int*)d_ws;
  unsigned short* xb       = (unsigned short*)d_ws + NCTR * CTRPAD * 2;
  unsigned short* h0seq    = xb + (long)NB * NT * NF;
  unsigned short* h1seq    = h0seq + (long)NT * HSEQSZ;

  cvt_x_kernel<<<dim3((NB * NT * NF) / (256 * 8)), dim3(256), 0, stream>>>(x, xb, counters);

  void* args[] = {&xb, &w0w, &w0b, &u0w, &u0b, &w1w, &w1b, &u1w, &u1b, &out,
                  &h0seq, &h1seq, &counters};
  (void)hipLaunchCooperativeKernel((const void*)lstm_fused_kernel,
                                   dim3(NBLK), dim3(NTHR), args, 0u, stream);
}

// Round 7
// 2110.044 us; speedup vs baseline: 4.6996x; 1.2621x over previous
//
#include <hip/hip_runtime.h>
#include <hip/hip_bf16.h>

typedef __bf16 bf16x8 __attribute__((ext_vector_type(8)));
typedef float  f32x4  __attribute__((ext_vector_type(4)));

#define NB    32                  // batch
#define NT    256                 // timesteps
#define NF    512                 // input features
#define NH    1024                // hidden
#define NBLK  256                 // grid blocks (1 per CU)
#define NTHR  512                 // threads per block (8 waves)
#define NCTR  64                  // barrier counters (4 blocks each)
#define CTRPAD 32                 // uints per counter (128B padding)
#define HSEQSZ (NB * NH)          // 32768 elems per timestep slab (bf16), layout [u][b]
#define PADK  8
#define LROW  (NH + PADK)         // 1032 (LDS row stride, elems)
#define H2SZ  (NB * NT * NH)      // h2 output elems
#define HHOFF H2SZ                // hh base in d_out
#define CCOFF (H2SZ + 2 * NB * NH)// cc base in d_out
#define LSTR  (NB * NH)           // layer stride inside hh/cc

__device__ __forceinline__ unsigned short f2bf(float f) {
  __bf16 h = (__bf16)f;
  return __builtin_bit_cast(unsigned short, h);
}

// ---------------- fp32 -> bf16 convert for x; also zeroes barrier counters ----------------
__global__ void cvt_x_kernel(const float* __restrict__ x, unsigned short* __restrict__ xb,
                             unsigned int* __restrict__ counters) {
  if (blockIdx.x == 0) {
    for (int i = threadIdx.x; i < NCTR * CTRPAD; i += 256) counters[i] = 0;
  }
  long i = (long)(blockIdx.x * blockDim.x + threadIdx.x) * 8;
  float4 a = *reinterpret_cast<const float4*>(x + i);
  float4 b = *reinterpret_cast<const float4*>(x + i + 4);
  uint4 o;
  o.x = (unsigned)f2bf(a.x) | ((unsigned)f2bf(a.y) << 16);
  o.y = (unsigned)f2bf(a.z) | ((unsigned)f2bf(a.w) << 16);
  o.z = (unsigned)f2bf(b.x) | ((unsigned)f2bf(b.y) << 16);
  o.w = (unsigned)f2bf(b.z) | ((unsigned)f2bf(b.w) << 16);
  *reinterpret_cast<uint4*>(xb + i) = o;
}

// Load N MFMA B-fragments for this wave into REGISTERS (fp32 global -> bf16).
template<int N>
__device__ __forceinline__ void load_wfrags(const float* __restrict__ W, int K, int kofs,
                                            int grow, int ksub, bf16x8* dst) {
#pragma unroll
  for (int ks = 0; ks < N; ++ks) {
    const float* p = W + (long)grow * K + kofs + ks * 32 + ksub * 8;
    float4 a = *reinterpret_cast<const float4*>(p);
    float4 b = *reinterpret_cast<const float4*>(p + 4);
    bf16x8 fr;
    fr[0]=(__bf16)a.x; fr[1]=(__bf16)a.y; fr[2]=(__bf16)a.z; fr[3]=(__bf16)a.w;
    fr[4]=(__bf16)b.x; fr[5]=(__bf16)b.y; fr[6]=(__bf16)b.z; fr[7]=(__bf16)b.w;
    dst[ks] = fr;
  }
}

// 8 ksteps over GLOBAL memory (xb only): stage 8 loads, then 8 MFMAs, 4 acc chains.
__device__ __forceinline__ void mac8(const unsigned short* __restrict__ ap,
                                     const bf16x8* wr, f32x4* ac) {
  bf16x8 st[8];
#pragma unroll
  for (int j = 0; j < 8; ++j) st[j] = *reinterpret_cast<const bf16x8*>(ap + j * 32);
#pragma unroll
  for (int j = 0; j < 8; ++j)
    ac[j & 3] = __builtin_amdgcn_mfma_f32_16x16x32_bf16(st[j], wr[j], ac[j & 3], 0, 0, 0);
}

__device__ __forceinline__ float sigm(float x) { return 1.f / (1.f + __expf(-x)); }

// Persistent fused 2-layer LSTM. 256 blocks x 512 threads (8 waves), 1 block/CU.
// h buffers are [t][unit][batch]: each block writes 2 FULL 128B lines per slab
// (no partial-line RMW); readers stage the 64KB slab cooperatively into LDS,
// transposed to [b][k] via per-thread 8x8 register transpose. Mac loops read LDS.
__global__ __launch_bounds__(NTHR, 2)
void lstm_fused_kernel(const unsigned short* __restrict__ xb,
                       const float* __restrict__ w0w, const float* __restrict__ w0b,
                       const float* __restrict__ u0w, const float* __restrict__ u0b,
                       const float* __restrict__ w1w, const float* __restrict__ w1b,
                       const float* __restrict__ u1w, const float* __restrict__ u1b,
                       float* __restrict__ out,
                       unsigned short* __restrict__ h0seq,
                       unsigned short* __restrict__ h1seq,
                       unsigned int* __restrict__ counters) {
  extern __shared__ char smem[];
  unsigned short (*h0l)[LROW] = (unsigned short (*)[LROW])smem;                       // 66KB
  unsigned short (*h1l)[LROW] = (unsigned short (*)[LROW])(smem + NB * LROW * 2);     // 66KB
  float (*gbuf)[NB * 17]      = (float (*)[NB * 17])(smem + 2 * NB * LROW * 2);       // 8.7KB

  const int tid  = threadIdx.x;
  const int blk  = blockIdx.x;
  const int wave = tid >> 6;
  const int lane = tid & 63;
  const int n16  = lane & 15;   // gate-col within slice / A row
  const int ksub = lane >> 4;   // k-subgroup
  const int ksub8 = ksub * 8;
  const int rt   = wave & 1;    // batch row-tile
  const int m0   = rt * 16 + n16;
  const int grow = (n16 >> 2) * NH + blk * 4 + (n16 & 3);

  // -------- one-time: weights into registers --------
  bf16x8 wreg[32];
  if (wave < 2) {
    load_wfrags<16>(w0w, NF, 0,   grow, ksub, wreg);       // x-proj (K=512)
    load_wfrags<16>(u0w, NH, 0,   grow, ksub, wreg + 16);  // h-part, k 0..511
  } else if (wave < 4) {
    load_wfrags<16>(u0w, NH, 512, grow, ksub, wreg);       // h-part, k 512..1023
  } else if (wave < 6) {
    load_wfrags<32>(w1w, NH, 0,   grow, ksub, wreg);       // L1 input-proj
  } else {
    load_wfrags<32>(u1w, NH, 0,   grow, ksub, wreg);       // L1 recurrence
  }

  // -------- per-thread phase-2 state: (u, b) mapping --------
  float bias0 = 0.f, bias1 = 0.f, bias2 = 0.f, bias3 = 0.f;
  int p2_u = 0, p2_b = 0, p2_hu = 0;
  if (tid < 256) {
    int rr = tid & 127;
    p2_u = rr >> 5; p2_b = rr & 31; p2_hu = blk * 4 + p2_u;
    const float* wb = (tid < 128) ? w0b : w1b;
    const float* ub = (tid < 128) ? u0b : u1b;
    bias0 = wb[0 * NH + p2_hu] + ub[0 * NH + p2_hu];
    bias1 = wb[1 * NH + p2_hu] + ub[1 * NH + p2_hu];
    bias2 = wb[2 * NH + p2_hu] + ub[2 * NH + p2_hu];
    bias3 = wb[3 * NH + p2_hu] + ub[3 * NH + p2_hu];
  }
  float c_state = 0.f;

  // cooperative slab stage: global [k][b] (contiguous) -> LDS [b][k] (padded)
  auto stage = [&](const unsigned short* __restrict__ src, unsigned short (*dst)[LROW]) {
    const int k0 = (tid >> 2) * 8;   // 128 k-tiles
    const int b0 = (tid & 3) * 8;    // 4 b-tiles
    unsigned r[8][4];
#pragma unroll
    for (int j = 0; j < 8; ++j) {
      uint4 v = *reinterpret_cast<const uint4*>(src + (k0 + j) * NB + b0);
      r[j][0] = v.x; r[j][1] = v.y; r[j][2] = v.z; r[j][3] = v.w;
    }
#pragma unroll
    for (int b = 0; b < 8; ++b) {
      uint4 o;
      unsigned w[4];
#pragma unroll
      for (int m = 0; m < 4; ++m) {
        unsigned lo = r[2 * m][b >> 1], hi = r[2 * m + 1][b >> 1];
        w[m] = (b & 1) ? ((lo >> 16) | (hi & 0xffff0000u))
                       : ((lo & 0xffffu) | (hi << 16));
      }
      o.x = w[0]; o.y = w[1]; o.z = w[2]; o.w = w[3];
      *reinterpret_cast<uint4*>(&dst[b0 + b][k0]) = o;
    }
  };

  // -------- prologue: x-projection for t=0 (w0/w1) --------
  f32x4 xa[4];
#pragma unroll
  for (int r = 0; r < 4; ++r) xa[r] = (f32x4){0.f, 0.f, 0.f, 0.f};
  if (wave < 2) {
    const unsigned short* xp = xb + ((long)m0 * NT + 0) * NF + ksub8;
    mac8(xp, wreg, xa); mac8(xp + 256, wreg + 8, xa);
  }

  for (int s = 0; s <= NT; ++s) {
    // ---------------- stage h slabs into LDS ----------------
    if (s >= 1) stage(h0seq + (long)(s - 1) * HSEQSZ, h0l);
    if (s >= 2) stage(h1seq + (long)(s - 2) * HSEQSZ, h1l);
    __syncthreads();

    // ---------------- phase 1: gate GEMM partials (LDS reads) ----------------
    if (wave < 2) {
      if (s < NT) {
        f32x4 ac[4] = {xa[0], xa[1], xa[2], xa[3]};
        if (s > 0) {
#pragma unroll
          for (int ks = 0; ks < 16; ++ks) {
            bf16x8 af = *reinterpret_cast<const bf16x8*>(&h0l[m0][ks * 32 + ksub8]);
            ac[ks & 3] = __builtin_amdgcn_mfma_f32_16x16x32_bf16(af, wreg[16 + ks], ac[ks & 3], 0, 0, 0);
          }
        }
        f32x4 acc = (ac[0] + ac[1]) + (ac[2] + ac[3]);
#pragma unroll
        for (int r = 0; r < 4; ++r) gbuf[0][(rt * 16 + ksub * 4 + r) * 17 + n16] = acc[r];
      }
    } else if (wave < 4) {
      if (s < NT) {
        f32x4 ac[4];
#pragma unroll
        for (int r = 0; r < 4; ++r) ac[r] = (f32x4){0.f, 0.f, 0.f, 0.f};
        if (s > 0) {
#pragma unroll
          for (int ks = 0; ks < 16; ++ks) {
            bf16x8 af = *reinterpret_cast<const bf16x8*>(&h0l[m0][512 + ks * 32 + ksub8]);
            ac[ks & 3] = __builtin_amdgcn_mfma_f32_16x16x32_bf16(af, wreg[ks], ac[ks & 3], 0, 0, 0);
          }
        }
        f32x4 acc = (ac[0] + ac[1]) + (ac[2] + ac[3]);
#pragma unroll
        for (int r = 0; r < 4; ++r) gbuf[1][(rt * 16 + ksub * 4 + r) * 17 + n16] = acc[r];
      }
    } else if (wave < 6) {
      if (s >= 1) {
        f32x4 ac[4];
#pragma unroll
        for (int r = 0; r < 4; ++r) ac[r] = (f32x4){0.f, 0.f, 0.f, 0.f};
#pragma unroll
        for (int ks = 0; ks < 32; ++ks) {
          bf16x8 af = *reinterpret_cast<const bf16x8*>(&h0l[m0][ks * 32 + ksub8]);
          ac[ks & 3] = __builtin_amdgcn_mfma_f32_16x16x32_bf16(af, wreg[ks], ac[ks & 3], 0, 0, 0);
        }
        f32x4 acc = (ac[0] + ac[1]) + (ac[2] + ac[3]);
#pragma unroll
        for (int r = 0; r < 4; ++r) gbuf[2][(rt * 16 + ksub * 4 + r) * 17 + n16] = acc[r];
      }
    } else {
      if (s >= 1) {
        f32x4 ac[4];
#pragma unroll
        for (int r = 0; r < 4; ++r) ac[r] = (f32x4){0.f, 0.f, 0.f, 0.f};
        if (s >= 2) {
#pragma unroll
          for (int ks = 0; ks < 32; ++ks) {
            bf16x8 af = *reinterpret_cast<const bf16x8*>(&h1l[m0][ks * 32 + ksub8]);
            ac[ks & 3] = __builtin_amdgcn_mfma_f32_16x16x32_bf16(af, wreg[ks], ac[ks & 3], 0, 0, 0);
          }
        }
        f32x4 acc = (ac[0] + ac[1]) + (ac[2] + ac[3]);
#pragma unroll
        for (int r = 0; r < 4; ++r) gbuf[3][(rt * 16 + ksub * 4 + r) * 17 + n16] = acc[r];
      }
    }
    __syncthreads();

    // ---------------- phase 2: activations + state update ----------------
    if (tid < 128) {
      if (s < NT) {
        int base = p2_b * 17;
        float gi = sigm(gbuf[0][base +  0 + p2_u] + gbuf[1][base +  0 + p2_u] + bias0);
        float gf = sigm(gbuf[0][base +  4 + p2_u] + gbuf[1][base +  4 + p2_u] + bias1);
        float gg = tanhf(gbuf[0][base +  8 + p2_u] + gbuf[1][base +  8 + p2_u] + bias2);
        float go = sigm(gbuf[0][base + 12 + p2_u] + gbuf[1][base + 12 + p2_u] + bias3);
        c_state = gf * c_state + gi * gg;
        float h = go * tanhf(c_state);
        unsigned hu16 = (unsigned)f2bf(h);
        unsigned other = __shfl_down(hu16, 1);
        if ((tid & 1) == 0) {   // pack (b, b+1): contiguous full-line block writes
          unsigned pk = hu16 | (other << 16);
          __hip_atomic_store((unsigned*)(h0seq + (long)s * HSEQSZ + p2_hu * NB + p2_b),
                             pk, __ATOMIC_RELAXED, __HIP_MEMORY_SCOPE_AGENT);
        }
        if (s == NT - 1) {
          out[HHOFF + 0 * LSTR + p2_b * NH + p2_hu] = h;
          out[CCOFF + 0 * LSTR + p2_b * NH + p2_hu] = c_state;
        }
      }
    } else if (tid < 256) {
      if (s >= 1) {
        int t = s - 1;
        int base = p2_b * 17;
        float gi = sigm(gbuf[2][base +  0 + p2_u] + gbuf[3][base +  0 + p2_u] + bias0);
        float gf = sigm(gbuf[2][base +  4 + p2_u] + gbuf[3][base +  4 + p2_u] + bias1);
        float gg = tanhf(gbuf[2][base +  8 + p2_u] + gbuf[3][base +  8 + p2_u] + bias2);
        float go = sigm(gbuf[2][base + 12 + p2_u] + gbuf[3][base + 12 + p2_u] + bias3);
        c_state = gf * c_state + gi * gg;
        float h = go * tanhf(c_state);
        unsigned hu16 = (unsigned)f2bf(h);
        unsigned other = __shfl_down(hu16, 1);
        if ((tid & 1) == 0) {
          unsigned pk = hu16 | (other << 16);
          __hip_atomic_store((unsigned*)(h1seq + (long)t * HSEQSZ + p2_hu * NB + p2_b),
                             pk, __ATOMIC_RELAXED, __HIP_MEMORY_SCOPE_AGENT);
        }
        if (t == NT - 1) {
          out[HHOFF + 1 * LSTR + p2_b * NH + p2_hu] = h;
          out[CCOFF + 1 * LSTR + p2_b * NH + p2_hu] = c_state;
        }
      }
    }

    // ---------------- grid barrier (relaxed; x-proj for s+1 hides under it) ----------------
    {
      if (wave < 4) asm volatile("s_waitcnt vmcnt(0)" ::: "memory");  // drain sc1 h stores
      __syncthreads();
      if (tid == 0)
        __hip_atomic_fetch_add(counters + (blk & (NCTR - 1)) * CTRPAD, 1u,
                               __ATOMIC_RELAXED, __HIP_MEMORY_SCOPE_AGENT);
      if (wave < 2) {   // compute next timestep's x-projection while waiting
#pragma unroll
        for (int r = 0; r < 4; ++r) xa[r] = (f32x4){0.f, 0.f, 0.f, 0.f};
        if (s + 1 < NT) {
          const unsigned short* xp = xb + ((long)m0 * NT + (s + 1)) * NF + ksub8;
          mac8(xp, wreg, xa); mac8(xp + 256, wreg + 8, xa);
        }
      }
      if (wave == 7) {  // single-wave poll: lane l watches counter l
        const unsigned target = (unsigned)(NBLK / NCTR) * (unsigned)(s + 1);
        unsigned int* pp = counters + (lane & (NCTR - 1)) * CTRPAD;
        for (;;) {
          unsigned v = __hip_atomic_load(pp, __ATOMIC_RELAXED, __HIP_MEMORY_SCOPE_AGENT);
          if (__all(v >= target)) break;
          __builtin_amdgcn_s_sleep(1);
        }
      }
      __syncthreads();
    }
  }

  // ---------------- epilogue: h2 write (bf16 h1seq [u][b] -> fp32 out [b][t][u]) ----------------
  // Block j owns timestep t=j; 8x8 register transpose per thread, 32B fp32 stores.
  {
    const unsigned short* src = h1seq + (long)blk * HSEQSZ;
    const int k0 = (tid >> 2) * 8;
    const int b0 = (tid & 3) * 8;
    unsigned r[8][4];
#pragma unroll
    for (int j = 0; j < 8; ++j) {
      uint4 v = *reinterpret_cast<const uint4*>(src + (k0 + j) * NB + b0);
      r[j][0] = v.x; r[j][1] = v.y; r[j][2] = v.z; r[j][3] = v.w;
    }
#pragma unroll
    for (int b = 0; b < 8; ++b) {
      float f[8];
#pragma unroll
      for (int j = 0; j < 8; ++j) {
        unsigned u16v = (b & 1) ? (r[j][b >> 1] >> 16) : (r[j][b >> 1] & 0xffffu);
        f[j] = __builtin_bit_cast(float, u16v << 16);
      }
      float* dst = out + ((long)(b0 + b) * NT + blk) * NH + k0;
      float4 lo4 = {f[0], f[1], f[2], f[3]};
      float4 hi4 = {f[4], f[5], f[6], f[7]};
      *reinterpret_cast<float4*>(dst)     = lo4;
      *reinterpret_cast<float4*>(dst + 4) = hi4;
    }
  }
}

extern "C" void kernel_launch(void* const* d_in, const int* in_sizes, int n_in,
                              void* d_out, int out_size, void* d_ws, size_t ws_size,
                              hipStream_t stream) {
  const float* x   = (const float*)d_in[0];
  const float* w0w = (const float*)d_in[1];
  const float* w0b = (const float*)d_in[2];
  const float* u0w = (const float*)d_in[3];
  const float* u0b = (const float*)d_in[4];
  const float* w1w = (const float*)d_in[5];
  const float* w1b = (const float*)d_in[6];
  const float* u1w = (const float*)d_in[7];
  const float* u1b = (const float*)d_in[8];
  float* out = (float*)d_out;

  // ws layout: [counters 8KB][xb bf16 8.4MB][h0seq bf16 16.8MB][h1seq bf16 16.8MB]
  unsigned int*   counters = (unsigned int*)d_ws;
  unsigned short* xb       = (unsigned short*)d_ws + NCTR * CTRPAD * 2;
  unsigned short* h0seq    = xb + (long)NB * NT * NF;
  unsigned short* h1seq    = h0seq + (long)NT * HSEQSZ;

  cvt_x_kernel<<<dim3((NB * NT * NF) / (256 * 8)), dim3(256), 0, stream>>>(x, xb, counters);

  size_t smem = (size_t)(2 * NB * LROW * 2) + 4 * (NB * 17) * sizeof(float);  // 140800
  (void)hipFuncSetAttribute((const void*)lstm_fused_kernel,
                            hipFuncAttributeMaxDynamicSharedMemorySize, (int)smem);

  void* args[] = {&xb, &w0w, &w0b, &u0w, &u0b, &w1w, &w1b, &u1w, &u1b, &out,
                  &h0seq, &h1seq, &counters};
  (void)hipLaunchCooperativeKernel((const void*)lstm_fused_kernel,
                                   dim3(NBLK), dim3(NTHR), args, (unsigned int)smem, stream);
}